// Round 8
// baseline (1007.877 us; speedup 1.0000x reference)
//
#include <hip/hip_runtime.h>
#include <cstdint>
#include <cstddef>

#define EE 2256
#define EP 2304

typedef __attribute__((ext_vector_type(8))) short bf16x8;
typedef __attribute__((ext_vector_type(4))) float f32x4;

__device__ __forceinline__ unsigned short f2b(float f){
  unsigned u = __builtin_bit_cast(unsigned, f);
  u += 0x7fffu + ((u>>16)&1u);
  return (unsigned short)(u>>16);
}
__device__ __forceinline__ float b2f(unsigned short h){
  unsigned u = ((unsigned)h)<<16; return __builtin_bit_cast(float, u);
}
__device__ __forceinline__ float sigm(float x){ return 1.f/(1.f+__expf(-x)); }
__device__ __forceinline__ float tanhfast(float x){ return 1.f - 2.f/(__expf(2.f*x)+1.f); }

// bijective XCD-chunked swizzle (m204)
__device__ __forceinline__ int xcd_swz(int bid, int nwg){
  int xcd = bid & 7, idx = bid >> 3;
  int q = nwg >> 3, r = nwg & 7;
  return (xcd < r ? xcd*(q+1) : r*(q+1) + (xcd-r)*q) + idx;
}

typedef __attribute__((address_space(3))) unsigned int lds_u32;
typedef __attribute__((address_space(1))) const unsigned int gbl_u32;
__device__ __forceinline__ void glds16(const void* g, void* l){
  __builtin_amdgcn_global_load_lds((gbl_u32*)g, (lds_u32*)l, 16, 0, 0);
}

// ---------------- utility kernels ----------------
__global__ __launch_bounds__(128) void gm_zero_pads(unsigned short* yp6, unsigned short* yp32,
                                                    unsigned short* yp16){
  int e = blockIdx.x; int tid = threadIdx.x;
  #pragma unroll
  for (int r=0; r<2; ++r){
    int row = r ? 49 : 0;
    if (tid < 8)  yp6 [((size_t)e*50+row)*8  + tid] = 0;
    if (tid < 32) yp32[((size_t)e*50+row)*32 + tid] = 0;
    if (tid < 16) yp16[((size_t)e*50+row)*16 + tid] = 0;
  }
}

__global__ __launch_bounds__(128) void gm_zero_pad128(unsigned short* yp128){
  int e = blockIdx.x; int tid = threadIdx.x;
  yp128[((size_t)e*50+0)*128 + tid] = 0;
  yp128[((size_t)e*50+49)*128 + tid] = 0;
}

__global__ void gm_prep_eeadj(const float* __restrict__ src, unsigned short* __restrict__ dst){
  int idx = blockIdx.x*256 + threadIdx.x;
  if (idx >= EP*EP) return;
  int r = idx / EP, k = idx - r*EP;
  float v = (r < EE && k < EE) ? src[(size_t)r*EE + k] : 0.f;
  dst[idx] = f2b(v);
}

__global__ void gm_prep_wall(const float* __restrict__ w0, const float* __restrict__ w1,
                             const float* __restrict__ w2, const float* __restrict__ w3,
                             const float* __restrict__ w4,
                             unsigned short* d0, unsigned short* d1, unsigned short* d2,
                             unsigned short* d3, unsigned short* d4){
  int idx = blockIdx.x*256 + threadIdx.x;
  const float* w; unsigned short* dp; int Co,Cin,KPT,Kpad,loc;
  if      (idx < 1024) { w=w0; dp=d0; Co=32;  Cin=6;   KPT=8;   Kpad=32;  loc=idx; }
  else if (idx < 4096) { w=w1; dp=d1; Co=32;  Cin=32;  KPT=32;  Kpad=96;  loc=idx-1024; }
  else if (idx < 53248){ w=w2; dp=d2; Co=128; Cin=128; KPT=128; Kpad=384; loc=idx-4096; }
  else if (idx < 57856){ w=w3; dp=d3; Co=16;  Cin=96;  KPT=96;  Kpad=288; loc=idx-53248; }
  else if (idx < 58880){ w=w4; dp=d4; Co=2;   Cin=16;  KPT=16;  Kpad=64;  loc=idx-57856; }
  else return;
  int co = loc / Kpad; int k = loc - co*Kpad;
  int t = k / KPT; int ci = k - t*KPT;
  float v = (co < Co && t < 3 && ci < Cin) ? w[((size_t)co*Cin + ci)*3 + t] : 0.f;
  dp[loc] = f2b(v);
}

// ---------------- message LSE kernels ----------------
__global__ __launch_bounds__(128) void gm_cmsg(const float* __restrict__ bi, const float* __restrict__ bij,
                                               float* __restrict__ cmi, float* __restrict__ cmj){
  int e = blockIdx.x; int tid = threadIdx.x;
  __shared__ float t[48*49]; __shared__ float bs[48], bd[48];
  const float* src = bij + (size_t)e*2304;
  for (int i=tid;i<2304;i+=128){ int r=i/48, c=i-r*48; t[r*49+c]=src[i]; }
  if (tid<48){ int s=e/47, m=e-s*47; int d=m+(m>=s); bs[tid]=bi[s*48+tid]; bd[tid]=bi[d*48+tid]; }
  __syncthreads();
  if (tid < 48){
    float mx=-1e30f;
    for (int n=0;n<48;n++) mx = fmaxf(mx, t[tid*49+n]+bd[n]);
    float sm=0.f;
    for (int n=0;n<48;n++) sm += __expf((t[tid*49+n]+bd[n]-mx)*20.f);
    cmi[e*48+tid] = mx + __logf(sm)*(1.f/20.f);
  } else if (tid>=64 && tid<112){
    int n = tid-64;
    float mx=-1e30f;
    for (int k=0;k<48;k++) mx = fmaxf(mx, t[k*49+n]+bs[k]);
    float sm=0.f;
    for (int k=0;k<48;k++) sm += __expf((t[k*49+n]+bs[k]-mx)*20.f);
    cmj[e*48+n] = mx + __logf(sm)*(1.f/20.f);
  }
}

__global__ __launch_bounds__(256) void gm_node_accum(const float* __restrict__ bij, const float* __restrict__ cmi,
                              const float* __restrict__ cmj, const float* __restrict__ msgi,
                              const float* __restrict__ msgj, const int* __restrict__ dec,
                              float* ncmi, float* ncmj, float* nnmi, float* nnmj,
                              float* o_f1, float* o_f2){
  int i = blockIdx.x; int tid = threadIdx.x;
  __shared__ float red[5][6][48];
  int mg = tid / 48;
  int w  = tid - mg*48;
  if (mg < 5){
    int dc = dec[i];
    float a1=0,a2=0,a3=0,a4=0,s1=0,s2=0;
    for (int m=mg; m<47; m+=5){
      int e1 = i*47+m;
      a1 += cmi[e1*48+w]; a3 += msgi[e1*48+w];
      s1 += bij[(size_t)e1*2304 + dc*48 + w];
      int j = m + (m>=i); int e2 = j*47 + i - (i>j);
      a2 += cmj[e2*48+w]; a4 += msgj[e2*48+w];
      s2 += bij[(size_t)e2*2304 + w*48 + dc];
    }
    red[mg][0][w]=a1; red[mg][1][w]=a2; red[mg][2][w]=a3;
    red[mg][3][w]=a4; red[mg][4][w]=s1; red[mg][5][w]=s2;
  }
  __syncthreads();
  if (tid < 48){
    float a1=0,a2=0,a3=0,a4=0,s1=0,s2=0;
    for (int g=0; g<5; g++){
      a1+=red[g][0][tid]; a2+=red[g][1][tid]; a3+=red[g][2][tid];
      a4+=red[g][3][tid]; s1+=red[g][4][tid]; s2+=red[g][5][tid];
    }
    ncmi[i*48+tid]=a1; ncmj[i*48+tid]=a2; nnmi[i*48+tid]=a3; nnmj[i*48+tid]=a4;
    o_f1[i*48+tid]=s1; o_f2[i*48+tid]=s2;
  }
}

// ---------------- staging builders ----------------
__global__ void gm_build_x6(const float* __restrict__ msgi, const float* __restrict__ msgj,
                            const float* __restrict__ cmi, const float* __restrict__ cmj,
                            const float* __restrict__ bi, unsigned short* __restrict__ x6){
  int idx = blockIdx.x*256 + threadIdx.x;
  if (idx >= 288*EP) return;
  int row = idx / EP, e = idx - row*EP;
  int w = row / 6, c = row - w*6;
  unsigned short val = 0;
  if (e < EE){
    int s = e/47, m = e-s*47, d = m + (m>=s);
    float x;
    switch(c){
      case 0: x = msgi[e*48+w]; break;
      case 1: x = msgj[e*48+w]; break;
      case 2: x = cmi[e*48+w]; break;
      case 3: x = cmj[e*48+w]; break;
      case 4: x = bi[s*48+w]; break;
      default: x = bi[d*48+w]; break;
    }
    val = f2b(x);
  }
  x6[idx] = val;
}

__global__ void gm_fill_x128_hi(const float* __restrict__ emem0, const float* __restrict__ nfeat,
                                unsigned short* __restrict__ x128){
  int idx = blockIdx.x*256 + threadIdx.x;
  if (idx >= 96*EP) return;
  int q = idx/EP; int c = 32 + q; int e = idx - q*EP;
  if (e >= EE){ for (int w=0;w<48;w++) x128[(size_t)(w*128+c)*EP + e] = 0; return; }
  int s=e/47, m=e-s*47, d=m+(m>=s);
  const float* srcrow;
  if (c < 64)      srcrow = nfeat + ((size_t)s*32 + (c-32))*48;
  else if (c < 96) srcrow = nfeat + ((size_t)d*32 + (c-64))*48;
  else             srcrow = emem0 + ((size_t)e*64 + (c-64))*48;
  #pragma unroll
  for (int w4=0; w4<12; w4++){
    float4 xv = *(const float4*)(srcrow + w4*4);
    x128[(size_t)((w4*4+0)*128+c)*EP + e] = f2b(xv.x);
    x128[(size_t)((w4*4+1)*128+c)*EP + e] = f2b(xv.y);
    x128[(size_t)((w4*4+2)*128+c)*EP + e] = f2b(xv.z);
    x128[(size_t)((w4*4+3)*128+c)*EP + e] = f2b(xv.w);
  }
}

// ---------------- MFMA map GEMM (single-buffer, col-major XCD chunking) ----------------
__global__ __launch_bounds__(256) void gm_map_gemm(
    const unsigned short* __restrict__ A, const unsigned short* __restrict__ BT,
    unsigned short* __restrict__ ypad, float* __restrict__ outf,
    const float* __restrict__ bias, int nrow, int Nvalid, int Cch, int Cslab,
    int do_relu, int f32_out)
{
  __shared__ __align__(16) unsigned short lA[128*32];
  __shared__ __align__(16) unsigned short lB[128*32];
  const int tid = threadIdx.x;
  const int lane = tid & 63, wid = tid >> 6;
  const int swz = xcd_swz(blockIdx.x, gridDim.x);
  const int m0 = (swz % nrow) * 128;
  const int n0 = (swz / nrow) * 128;
  const int wm = wid >> 1, wn = wid & 1;
  f32x4 acc[4][4];
  #pragma unroll
  for (int i=0;i<4;i++){
    #pragma unroll
    for (int j=0;j<4;j++) acc[i][j] = f32x4{0.f,0.f,0.f,0.f};
  }
  const int srow = (lane>>2), scol = (lane&3);

  for (int ks = 0; ks < EP/32; ++ks) {
    #pragma unroll
    for (int q=0;q<2;q++){
      int chunk = wid*2+q;
      int row = chunk*16 + srow;
      int off = (scol*16) ^ (((row>>1)&3)<<4);
      glds16((const char*)A  + (size_t)(m0+row)*(EP*2) + ks*64 + off, (char*)lA + chunk*1024);
      glds16((const char*)BT + (size_t)(n0+row)*(EP*2) + ks*64 + off, (char*)lB + chunk*1024);
    }
    __syncthreads();
    bf16x8 af[4], bfr[4];
    #pragma unroll
    for (int mi=0;mi<4;mi++){
      int row = wm*64 + mi*16 + (lane&15);
      int off = ((lane>>4)*16) ^ (((row>>1)&3)<<4);
      af[mi] = *(const bf16x8*)((const char*)lA + row*64 + off);
    }
    #pragma unroll
    for (int ni=0;ni<4;ni++){
      int row = wn*64 + ni*16 + (lane&15);
      int off = ((lane>>4)*16) ^ (((row>>1)&3)<<4);
      bfr[ni] = *(const bf16x8*)((const char*)lB + row*64 + off);
    }
    #pragma unroll
    for (int mi=0;mi<4;mi++){
      #pragma unroll
      for (int ni=0;ni<4;ni++)
        acc[mi][ni] = __builtin_amdgcn_mfma_f32_16x16x32_bf16(af[mi], bfr[ni], acc[mi][ni], 0,0,0);
    }
    __syncthreads();
  }
  #pragma unroll
  for (int mi=0;mi<4;mi++){
    int ebase = m0 + wm*64 + mi*16 + (lane>>4)*4;
    #pragma unroll
    for (int ni=0;ni<4;ni++){
      int c = n0 + wn*64 + ni*16 + (lane&15);
      if (c >= Nvalid) continue;
      int w = c / Cch, ci = c - w*Cch;
      float bv = bias ? bias[ci] : 0.f;
      #pragma unroll
      for (int r=0;r<4;r++){
        int e = ebase + r;
        if (e >= EE) continue;
        float x = acc[mi][ni][r] + bv;
        if (do_relu) x = fmaxf(x, 0.f);
        if (f32_out) outf[(size_t)e*Nvalid + c] = x;
        else ypad[((size_t)e*50 + 1 + w)*Cslab + ci] = f2b(x);
      }
    }
  }
}

// split-K variant (single-buffer): writes f32 partials pbuf[sp][e][c]
__global__ __launch_bounds__(256) void gm_map_sk(
    const unsigned short* __restrict__ A, const unsigned short* __restrict__ BT,
    float* __restrict__ pbuf, int nrow, int ncol, int S, int kspan)
{
  __shared__ __align__(16) unsigned short lA[128*32];
  __shared__ __align__(16) unsigned short lB[128*32];
  const int tid = threadIdx.x;
  const int lane = tid & 63, wid = tid >> 6;
  const int swz = xcd_swz(blockIdx.x, gridDim.x);
  const int ntile = nrow*ncol;
  const int sp = swz / ntile;
  const int tile = swz - sp*ntile;
  const int m0 = (tile % nrow) * 128;
  const int n0 = (tile / nrow) * 128;
  const int Npad = ncol*128;
  const int k0 = sp*kspan, k1 = k0 + kspan;
  const int wm = wid >> 1, wn = wid & 1;
  f32x4 acc[4][4];
  #pragma unroll
  for (int i=0;i<4;i++){
    #pragma unroll
    for (int j=0;j<4;j++) acc[i][j] = f32x4{0.f,0.f,0.f,0.f};
  }
  const int srow = (lane>>2), scol = (lane&3);

  for (int ks = k0; ks < k1; ++ks){
    #pragma unroll
    for (int q=0;q<2;q++){
      int chunk = wid*2+q;
      int row = chunk*16 + srow;
      int off = (scol*16) ^ (((row>>1)&3)<<4);
      glds16((const char*)A  + (size_t)(m0+row)*(EP*2) + ks*64 + off, (char*)lA + chunk*1024);
      glds16((const char*)BT + (size_t)(n0+row)*(EP*2) + ks*64 + off, (char*)lB + chunk*1024);
    }
    __syncthreads();
    bf16x8 af[4], bfr[4];
    #pragma unroll
    for (int mi=0;mi<4;mi++){
      int row = wm*64 + mi*16 + (lane&15);
      int off = ((lane>>4)*16) ^ (((row>>1)&3)<<4);
      af[mi] = *(const bf16x8*)((const char*)lA + row*64 + off);
    }
    #pragma unroll
    for (int ni=0;ni<4;ni++){
      int row = wn*64 + ni*16 + (lane&15);
      int off = ((lane>>4)*16) ^ (((row>>1)&3)<<4);
      bfr[ni] = *(const bf16x8*)((const char*)lB + row*64 + off);
    }
    #pragma unroll
    for (int mi=0;mi<4;mi++){
      #pragma unroll
      for (int ni=0;ni<4;ni++)
        acc[mi][ni] = __builtin_amdgcn_mfma_f32_16x16x32_bf16(af[mi], bfr[ni], acc[mi][ni], 0,0,0);
    }
    __syncthreads();
  }
  float* pb = pbuf + (size_t)sp*2304*Npad;
  #pragma unroll
  for (int mi=0;mi<4;mi++){
    int ebase = m0 + wm*64 + mi*16 + (lane>>4)*4;
    #pragma unroll
    for (int ni=0;ni<4;ni++){
      int c = n0 + wn*64 + ni*16 + (lane&15);
      #pragma unroll
      for (int r=0;r<4;r++)
        pb[(size_t)(ebase+r)*Npad + c] = acc[mi][ni][r];
    }
  }
}

__global__ void gm_sk_fin(const float* __restrict__ pbuf, unsigned short* __restrict__ ypad,
                          float* __restrict__ outf, const float* __restrict__ bias,
                          int S, int Npad, int Nvalid, int Cch, int Cslab, int do_relu, int f32_out){
  int idx = blockIdx.x*256 + threadIdx.x;
  if (idx >= EE*Nvalid) return;
  int e = idx / Nvalid, c = idx - e*Nvalid;
  float s = 0.f;
  for (int p=0;p<S;p++) s += pbuf[(size_t)p*2304*Npad + (size_t)e*Npad + c];
  int w = c / Cch, ci = c - w*Cch;
  if (bias) s += bias[ci];
  if (do_relu) s = fmaxf(s, 0.f);
  if (f32_out) outf[(size_t)e*Nvalid + c] = s;
  else ypad[((size_t)e*50 + 1 + w)*Cslab + ci] = f2b(s);
}

// ---------------- MFMA conv GEMM (operand-swapped, single-buffer) ----------------
template<int BM>
__global__ __launch_bounds__(256) void gm_conv_gemm(
    const unsigned short* __restrict__ Wp, const unsigned short* __restrict__ ypad,
    unsigned short* __restrict__ outT, const float* __restrict__ bias,
    int Cch, int KPT, int Kpad, int Co, int Ct, int do_relu)
{
  constexpr int MI = (BM==128)?4:((BM==32)?2:1);
  constexpr int NI = (BM==128)?4:2;
  __shared__ __align__(16) unsigned short lA[BM*32];
  __shared__ __align__(16) unsigned short lB[128*32];
  const int tid = threadIdx.x, lane = tid&63, wid = tid>>6;
  const int swz = xcd_swz(blockIdx.x, 864);
  const int e0 = (swz / 48) * 128;
  const int w  = swz % 48;
  const int rowb = (BM==128)? (wid>>1)*64 : 0;
  const int colb = (BM==128)? (wid&1)*64 : wid*32;
  f32x4 acc[MI][NI];
  #pragma unroll
  for (int i=0;i<MI;i++){
    #pragma unroll
    for (int j=0;j<NI;j++) acc[i][j] = f32x4{0.f,0.f,0.f,0.f};
  }
  const int srow=(lane>>2), scol=(lane&3);
  const int ksteps = Kpad/32;
  for (int ks=0; ks<ksteps; ++ks){
    for (int c = wid; c < BM/16; c += 4){
      int row = c*16 + srow;
      int off = (scol*16) ^ (((row>>1)&3)<<4);
      glds16((const char*)Wp + (size_t)row*(Kpad*2) + ks*64 + off, (char*)lA + c*1024);
    }
    for (int c = wid; c < 8; c += 4){
      int row = c*16 + srow;
      int off = (scol*16) ^ (((row>>1)&3)<<4);
      int kg = ks*32 + (off>>1);
      int t = kg / KPT;
      int ci = kg - t*KPT;
      int e = e0 + row;
      const char* src;
      if (t < 3 && e < EE) src = (const char*)ypad + ((size_t)(e*50 + w + t)*Cch + ci)*2;
      else                 src = (const char*)ypad;
      glds16(src, (char*)lB + c*1024);
    }
    __syncthreads();
    bf16x8 af[MI], bfr[NI];
    #pragma unroll
    for (int mi=0;mi<MI;mi++){
      int row = rowb + mi*16 + (lane&15);
      int off = ((lane>>4)*16) ^ (((row>>1)&3)<<4);
      af[mi] = *(const bf16x8*)((const char*)lA + row*64 + off);
    }
    #pragma unroll
    for (int ni=0;ni<NI;ni++){
      int row = colb + ni*16 + (lane&15);
      int off = ((lane>>4)*16) ^ (((row>>1)&3)<<4);
      bfr[ni] = *(const bf16x8*)((const char*)lB + row*64 + off);
    }
    #pragma unroll
    for (int mi=0;mi<MI;mi++){
      #pragma unroll
      for (int ni=0;ni<NI;ni++)
        acc[mi][ni] = __builtin_amdgcn_mfma_f32_16x16x32_bf16(af[mi], bfr[ni], acc[mi][ni], 0,0,0);
    }
    __syncthreads();
  }
  #pragma unroll
  for (int mi=0;mi<MI;mi++){
    #pragma unroll
    for (int ni=0;ni<NI;ni++){
      int m = colb + ni*16 + (lane&15);
      int e = e0 + m;
      if (e >= EE) continue;
      #pragma unroll
      for (int r=0;r<4;r++){
        int co = rowb + mi*16 + (lane>>4)*4 + r;
        if (co >= Co) continue;
        float x = acc[mi][ni][r] + (bias ? bias[co] : 0.f);
        if (do_relu) x = fmaxf(x, 0.f);
        outT[((size_t)(w*Ct + co))*EP + e] = f2b(x);
      }
    }
  }
}

// ---------------- node-side kernels ----------------
__global__ void gm_build_nf(const float* __restrict__ bi, const float* __restrict__ v,
                            const float* __restrict__ nnmi, const float* __restrict__ nnmj,
                            const float* __restrict__ ncmi, const float* __restrict__ ncmj,
                            const float* __restrict__ f1, const float* __restrict__ f2,
                            float* __restrict__ nf){
  int idx = blockIdx.x*256+threadIdx.x;
  if (idx >= 48*8*48) return;
  int i = idx/(8*48); int rem = idx - i*(8*48); int c = rem/48; int w = rem-c*48;
  int iw = i*48+w;
  float x;
  switch(c){
    case 0: x=bi[iw]; break;
    case 1: x=bi[iw]+v[w]; break;
    case 2: x=nnmi[iw]; break;
    case 3: x=nnmj[iw]; break;
    case 4: x=ncmi[iw]; break;
    case 5: x=ncmj[iw]; break;
    case 6: x=f1[iw]; break;
    default: x=f2[iw]; break;
  }
  nf[idx]=x;
}

// fused nmap + nconv: block per node i; mapped features staged in LDS (Cin <= 96)
__global__ __launch_bounds__(256) void gm_mapconv(const float* __restrict__ adj,
    const float* __restrict__ X, const float* __restrict__ wgt, const float* __restrict__ bias,
    float* __restrict__ Y, int Cin, int Co, int relu){
  int i = blockIdx.x;
  __shared__ float t[96*48];
  __shared__ float arow[48];
  int tid = threadIdx.x;
  if (tid < 48) arow[tid] = adj[i*48+tid];
  __syncthreads();
  for (int cw = tid; cw < Cin*48; cw += 256){
    float s = 0.f;
    for (int j=0;j<48;j++) s += arow[j] * X[(size_t)j*Cin*48 + cw];
    t[cw] = s;
  }
  __syncthreads();
  for (int cow = tid; cow < Co*48; cow += 256){
    int co = cow/48, w = cow-co*48;
    float s = bias[co];
    const float* wb = wgt + (size_t)co*Cin*3;
    for (int ci=0; ci<Cin; ++ci){
      const float* xr = t + ci*48;
      float w0=wb[ci*3], w1=wb[ci*3+1], w2=wb[ci*3+2];
      if (w>0) s += xr[w-1]*w0;
      s += xr[w]*w1;
      if (w<47) s += xr[w+1]*w2;
    }
    if (relu) s = fmaxf(s,0.f);
    Y[(size_t)i*Co*48 + cow] = s;
  }
}

// fused nmap(128) + gate conv + LSTM pointwise (node side); block per node i
__global__ __launch_bounds__(512) void gm_mapconv_lstm(const float* __restrict__ adj,
    const float* __restrict__ X, const float* __restrict__ wgt, const float* __restrict__ bias,
    const float* __restrict__ nmem0, float* __restrict__ o_nmem, float* __restrict__ nfeat2){
  int i = blockIdx.x;
  __shared__ float t[128*48];
  __shared__ float arow[48];
  int tid = threadIdx.x;
  if (tid < 48) arow[tid] = adj[i*48+tid];
  __syncthreads();
  for (int cw = tid; cw < 128*48; cw += 512){
    float s = 0.f;
    for (int j=0;j<48;j++) s += arow[j] * X[(size_t)j*6144 + cw];
    t[cw] = s;
  }
  __syncthreads();
  for (int chw = tid; chw < 32*48; chw += 512){
    int ch = chw/48, w = chw-ch*48;
    float s0=bias[ch], s1=bias[32+ch], s2=bias[64+ch], s3=bias[96+ch];
    for (int ci=0; ci<128; ++ci){
      const float* xr = t + ci*48;
      float xm = (w>0)? xr[w-1] : 0.f;
      float xc = xr[w];
      float xp = (w<47)? xr[w+1] : 0.f;
      const float* wb0 = wgt + ((size_t)ch*128+ci)*3;
      const float* wb1 = wgt + ((size_t)(32+ch)*128+ci)*3;
      const float* wb2 = wgt + ((size_t)(64+ch)*128+ci)*3;
      const float* wb3 = wgt + ((size_t)(96+ch)*128+ci)*3;
      s0 += xm*wb0[0]+xc*wb0[1]+xp*wb0[2];
      s1 += xm*wb1[0]+xc*wb1[1]+xp*wb1[2];
      s2 += xm*wb2[0]+xc*wb2[1]+xp*wb2[2];
      s3 += xm*wb3[0]+xc*wb3[1]+xp*wb3[2];
    }
    float c = nmem0[((size_t)i*64+ch)*48+w];
    float c2 = sigm(s1)*c + sigm(s0)*tanhfast(s2);
    float h2 = sigm(s3)*tanhfast(c2);
    o_nmem[((size_t)i*64+ch)*48+w] = c2;
    o_nmem[((size_t)i*64+32+ch)*48+w] = h2;
    nfeat2[((size_t)i*32+ch)*48+w] = h2;
  }
}

// row-wise eton gathers from x128t efeat rows -> xn channels 32..95
__global__ __launch_bounds__(256) void gm_eton_x128(const unsigned short* __restrict__ x128,
                                                    float* __restrict__ xn){
  int row = blockIdx.x;          // w*32+cc
  int w = row >> 5, cc = row & 31;
  __shared__ float L[2256];
  const unsigned short* src = x128 + (size_t)(w*128 + cc)*EP;
  for (int t=threadIdx.x; t<2256; t+=256) L[t] = b2f(src[t]);
  __syncthreads();
  int tid = threadIdx.x;
  if (tid < 48){
    int i = tid; float s=0.f;
    for (int m=0;m<47;m++) s += L[i*47+m];
    xn[((size_t)i*128 + 32 + cc)*48 + w] = s;
  } else if (tid >= 64 && tid < 112){
    int i = tid-64; float s=0.f;
    for (int m=0;m<47;m++){
      int j = m + (m>=i);
      s += L[j*47 + i - (i>j)];
    }
    xn[((size_t)i*128 + 64 + cc)*48 + w] = s;
  }
}

__global__ void gm_xnode_copy(const float* __restrict__ nfeat, const float* __restrict__ nmem0,
                              float* __restrict__ xn){
  int idx = blockIdx.x*256+threadIdx.x;
  if (idx >= 48*64*48) return;
  int i = idx/(64*48); int rem = idx - i*(64*48); int c = rem/48; int w = rem-c*48;
  if (c < 32) xn[((size_t)i*128 + c)*48 + w] = nfeat[((size_t)i*32+c)*48+w];
  else        xn[((size_t)i*128 + 96 + (c-32))*48 + w] = nmem0[((size_t)i*64 + 32 + (c-32))*48 + w];
}

__global__ __launch_bounds__(256) void gm_elstm_pw(const unsigned short* __restrict__ gatesT,
                                                   const float* __restrict__ emem0,
                                                   float* __restrict__ o_emem){
  int bid = blockIdx.x;
  int e4 = bid / 6, chunk = bid - e4*6;
  int cw = chunk*256 + threadIdx.x;
  int ch = cw / 48, w = cw - ch*48;
  int ebase = e4*4;
  const unsigned short* g0 = gatesT + (size_t)(w*128 + ch)*EP + ebase;
  ushort4 vi = *(const ushort4*)(g0);
  ushort4 vf = *(const ushort4*)(g0 + (size_t)32*EP);
  ushort4 vg = *(const ushort4*)(g0 + (size_t)64*EP);
  ushort4 vo = *(const ushort4*)(g0 + (size_t)96*EP);
  const unsigned short* pi = (const unsigned short*)&vi;
  const unsigned short* pf = (const unsigned short*)&vf;
  const unsigned short* pg = (const unsigned short*)&vg;
  const unsigned short* po = (const unsigned short*)&vo;
  #pragma unroll
  for (int r=0;r<4;r++){
    int e = ebase + r;
    float gi = b2f(pi[r]), gf = b2f(pf[r]), gg = b2f(pg[r]), go = b2f(po[r]);
    float c  = emem0[((size_t)e*64 + ch)*48 + w];
    float c2 = sigm(gf)*c + sigm(gi)*tanhfast(gg);
    float h2 = sigm(go)*tanhfast(c2);
    o_emem[((size_t)e*64 + ch)*48 + w] = c2;
    o_emem[((size_t)e*64 + 32+ch)*48 + w] = h2;
  }
}

__global__ __launch_bounds__(256) void gm_eton_h(const float* __restrict__ o_emem,
                                                 float* __restrict__ x2){
  int row = blockIdx.x; int w = row >> 5, cc = row & 31;
  __shared__ float L[2256];
  for (int t=threadIdx.x; t<2256; t+=256)
    L[t] = o_emem[((size_t)t*64 + 32 + cc)*48 + w];
  __syncthreads();
  int tid = threadIdx.x;
  if (tid < 48){
    int i=tid; float s=0.f;
    for (int m=0;m<47;m++) s += L[i*47+m];
    x2[((size_t)i*96 + 32 + cc)*48 + w] = s;
  } else if (tid>=64 && tid<112){
    int i=tid-64; float s=0.f;
    for (int m=0;m<47;m++){ int j=m+(m>=i); s += L[j*47 + i - (i>j)]; }
    x2[((size_t)i*96 + 64 + cc)*48 + w] = s;
  }
}

__global__ void gm_x2_copy(const float* __restrict__ nfeat2, float* __restrict__ x2){
  int idx = blockIdx.x*256+threadIdx.x;
  if (idx >= 48*32*48) return;
  int i = idx/(32*48); int rem = idx - i*(32*48); int c = rem/48; int w = rem-c*48;
  x2[((size_t)i*96 + c)*48 + w] = nfeat2[idx];
}

__global__ __launch_bounds__(128) void gm_build_xpp(const float* __restrict__ o_emem,
                                                    const float* __restrict__ nfeat2,
                                                    unsigned short* __restrict__ xpp){
  int e = blockIdx.x; int tid = threadIdx.x;
  __shared__ float h[1536];
  __shared__ float sn[3072];
  int s = e/47; int m = e - s*47; int d = m + (m>=s);
  const float* src = o_emem + ((size_t)e*64 + 32)*48;
  for (int i=tid;i<1536;i+=128) h[i]=src[i];
  const float* ps = nfeat2 + (size_t)s*32*48;
  const float* pd = nfeat2 + (size_t)d*32*48;
  for (int i=tid;i<1536;i+=128){ sn[i]=ps[i]; sn[1536+i]=pd[i]; }
  if (tid < 96){
    xpp[((size_t)e*50 + 0)*96 + tid] = 0;
    xpp[((size_t)e*50 + 49)*96 + tid] = 0;
  }
  __syncthreads();
  for (int w=0; w<48; w++){
    if (tid < 96){
      float x;
      if (tid<32) x = h[tid*48+w];
      else x = sn[(tid-32)*48 + w];
      xpp[((size_t)e*50 + 1 + w)*96 + tid] = f2b(x);
    }
  }
}

__global__ void gm_nv(const float* __restrict__ nfpp, const float* __restrict__ v,
                      float* __restrict__ nv, float* __restrict__ o_v){
  int w = threadIdx.x;
  if (w<48){
    float s=0.f; for (int i=0;i<48;i++) s += nfpp[i*48+w];
    s *= (1.f/48.f);
    nv[w]=s; o_v[w]=v[w]+s;
  }
}

// fused: nmsg + bij output + edge LSE
__global__ __launch_bounds__(256) void gm_bijout(const float* __restrict__ bij,
                                                 const float* __restrict__ effpp,
                                                 const float* __restrict__ cmi, const float* __restrict__ cmj,
                                                 const float* __restrict__ msgi, const float* __restrict__ msgj,
                                                 float* __restrict__ nmi, float* __restrict__ nmj,
                                                 float* __restrict__ o_mi, float* __restrict__ o_mj,
                                                 float* __restrict__ o_bij, float* __restrict__ lse_e){
  int e = blockIdx.x; int tid = threadIdx.x;
  __shared__ float ri[48], rj[48], red[8];
  if (tid < 48){
    int idx = e*48+tid;
    float a = effpp[(size_t)e*96 + tid*2] + 0.5f*cmi[idx] - msgi[idx];
    ri[tid] = a; nmi[idx] = a; o_mi[idx] = msgi[idx] + a;
  } else if (tid >= 64 && tid < 112){
    int t2 = tid-64; int idx = e*48+t2;
    float b = effpp[(size_t)e*96 + t2*2 + 1] + 0.5f*cmj[idx] - msgj[idx];
    rj[t2] = b; nmj[idx] = b; o_mj[idx] = msgj[idx] + b;
  }
  __syncthreads();
  float v[9]; float mx = -1e30f;
  const float* src = bij + (size_t)e*2304;
  float* dst = o_bij + (size_t)e*2304;
  #pragma unroll
  for (int q=0;q<9;q++){
    int idx = q*256 + tid;
    int r = idx/48, c = idx-r*48;
    float x = src[idx] - ri[r] - rj[c];
    dst[idx] = x; v[q] = x; mx = fmaxf(mx, x);
  }
  for (int o=1;o<64;o<<=1) mx = fmaxf(mx, __shfl_xor(mx, o, 64));
  int lane = tid&63, w4 = tid>>6;
  if (lane==0) red[w4] = mx;
  __syncthreads();
  mx = fmaxf(fmaxf(red[0],red[1]),fmaxf(red[2],red[3]));
  float s = 0.f;
  #pragma unroll
  for (int q=0;q<9;q++) s += __expf((v[q]-mx)*20.f);
  for (int o=1;o<64;o<<=1) s += __shfl_xor(s, o, 64);
  if (lane==0) red[4+w4] = s;
  __syncthreads();
  if (tid==0){
    float t = red[4]+red[5]+red[6]+red[7];
    lse_e[e] = mx + __logf(t)*(1.f/20.f);
  }
}

__global__ void gm_biout(const float* __restrict__ bi, const float* __restrict__ nmi,
                         const float* __restrict__ nmj, const float* __restrict__ nv,
                         float* __restrict__ o_bi, float* __restrict__ lse_n){
  int i = blockIdx.x; int w = threadIdx.x;
  float val = -1e30f;
  if (w < 48){
    float s = 0.f;
    for (int m=0;m<47;m++){
      int e1 = i*47+m;
      s += nmi[e1*48+w];
      int j = m + (m>=i);
      int e2 = j*47 + i - (i>j);
      s += nmj[e2*48+w];
    }
    val = bi[i*48+w] + s - nv[w];
    o_bi[i*48+w] = val;
  }
  float mx = val;
  for (int o=1;o<64;o<<=1) mx = fmaxf(mx, __shfl_xor(mx, o, 64));
  float ex = (w<48)? __expf((val-mx)*20.f) : 0.f;
  for (int o=1;o<64;o<<=1) ex += __shfl_xor(ex, o, 64);
  if (w==0) lse_n[i] = mx + __logf(ex)*(1.f/20.f);
}

__global__ void gm_cdual(const float* __restrict__ lse_e, const float* __restrict__ lse_n,
                         const float* __restrict__ vout, float* __restrict__ out){
  int tid = threadIdx.x;
  float s = 0.f;
  for (int i=tid;i<EE;i+=256) s += lse_e[i];
  if (tid<48) s += lse_n[tid] + vout[tid];
  __shared__ float red[4];
  for (int o=1;o<64;o<<=1) s += __shfl_xor(s,o,64);
  if ((tid&63)==0) red[tid>>6]=s;
  __syncthreads();
  if (tid==0) out[0] = red[0]+red[1]+red[2]+red[3];
}

// ---------------- workspace layout ----------------
static constexpr size_t A256v(size_t x){ return (x+255)&~(size_t)255; }
static constexpr size_t OFF_EEADJ = 0;
static constexpr size_t OFF_X6T   = A256v(OFF_EEADJ + (size_t)EP*EP*2);
static constexpr size_t OFF_X32T  = A256v(OFF_X6T  + (size_t)384*EP*2);
static constexpr size_t OFF_X128T = A256v(OFF_X32T + (size_t)1536*EP*2);
static constexpr size_t OFF_YP6   = A256v(OFF_X128T + (size_t)6144*EP*2);
static constexpr size_t OFF_YP32  = A256v(OFF_YP6  + (size_t)EE*50*8*2);
static constexpr size_t OFF_YP128 = A256v(OFF_YP32 + (size_t)EE*50*32*2);
static constexpr size_t OFF_YP16  = A256v(OFF_YP128 + (size_t)EE*50*128*2);
static constexpr size_t OFF_ZEND  = A256v(OFF_YP16 + (size_t)EE*50*16*2 + 256);
static constexpr size_t OFF_XPP   = OFF_YP128;
static constexpr size_t OFF_SKP   = OFF_YP128;
static constexpr size_t OFF_WC0 = OFF_ZEND;
static constexpr size_t OFF_WC1 = A256v(OFF_WC0 + 32*32*2);
static constexpr size_t OFF_WCL = A256v(OFF_WC1 + 32*96*2);
static constexpr size_t OFF_WP0 = A256v(OFF_WCL + 128*384*2);
static constexpr size_t OFF_WP1 = A256v(OFF_WP0 + 16*288*2);
static constexpr size_t OFF_CMI = A256v(OFF_WP1 + 16*64*2);
static constexpr size_t OFF_CMJ = A256v(OFF_CMI + (size_t)EE*48*4);
static constexpr size_t OFF_NMI = A256v(OFF_CMJ + (size_t)EE*48*4);
static constexpr size_t OFF_NMJ = A256v(OFF_NMI + (size_t)EE*48*4);
static constexpr size_t OFF_EFPP= A256v(OFF_NMJ + (size_t)EE*48*4);
static constexpr size_t OFF_LSEE= A256v(OFF_EFPP + (size_t)EE*96*4);
static constexpr size_t OFF_LSEN= A256v(OFF_LSEE + EE*4);
static constexpr size_t OFF_NV  = A256v(OFF_LSEN + 48*4);
static constexpr size_t OFF_NF  = A256v(OFF_NV + 48*4);
static constexpr size_t OFF_NT2 = A256v(OFF_NF + (size_t)48*8*48*4);
static constexpr size_t OFF_NFEAT = A256v(OFF_NT2 + (size_t)48*32*48*4);
static constexpr size_t OFF_NFEAT2= A256v(OFF_NFEAT + (size_t)48*32*48*4);
static constexpr size_t OFF_XN  = A256v(OFF_NFEAT2 + (size_t)48*32*48*4);
static constexpr size_t OFF_NFPP= A256v(OFF_XN + (size_t)48*128*48*4);
static constexpr size_t OFF_NAC = A256v(OFF_NFPP + (size_t)48*48*4);

extern "C" void kernel_launch(void* const* d_in, const int* in_sizes, int n_in,
                              void* d_out, int out_size, void* d_ws, size_t ws_size,
                              hipStream_t stream) {
  const float* bi    = (const float*)d_in[0];
  const float* bij   = (const float*)d_in[1];
  const float* msgi  = (const float*)d_in[2];
  const float* msgj  = (const float*)d_in[3];
  const float* v_in  = (const float*)d_in[4];
  const float* nmem0 = (const float*)d_in[5];
  const float* emem0 = (const float*)d_in[6];
  const float* neadj = (const float*)d_in[7];
  const float* eeadj = (const float*)d_in[8];
  const int*   dec   = (const int*)d_in[13];
  const float* fm_w0 = (const float*)d_in[14]; const float* fm_b0 = (const float*)d_in[15];
  const float* fm_w1 = (const float*)d_in[16]; const float* fm_b1 = (const float*)d_in[17];
  const float* efm_w0= (const float*)d_in[18]; const float* efm_b0= (const float*)d_in[19];
  const float* efm_w1= (const float*)d_in[20]; const float* efm_b1= (const float*)d_in[21];
  const float* nl_w  = (const float*)d_in[22]; const float* nl_b  = (const float*)d_in[23];
  const float* el_w  = (const float*)d_in[24]; const float* el_b  = (const float*)d_in[25];
  const float* pp_w0 = (const float*)d_in[26]; const float* pp_b0 = (const float*)d_in[27];
  const float* pp_w1 = (const float*)d_in[28]; const float* pp_b1 = (const float*)d_in[29];
  const float* epp_w0= (const float*)d_in[30]; const float* epp_b0= (const float*)d_in[31];
  const float* epp_w1= (const float*)d_in[32]; const float* epp_b1= (const float*)d_in[33];

  char* ws = (char*)d_ws;
  unsigned short* eeadjb = (unsigned short*)(ws + OFF_EEADJ);
  unsigned short* x6t    = (unsigned short*)(ws + OFF_X6T);
  unsigned short* x32t   = (unsigned short*)(ws + OFF_X32T);
  unsigned short* x128t  = (unsigned short*)(ws + OFF_X128T);
  unsigned short* z1t    = x32t;
  unsigned short* z2t    = x6t;
  unsigned short* gatesT = x128t;
  unsigned short* yp6    = (unsigned short*)(ws + OFF_YP6);
  unsigned short* yp32   = (unsigned short*)(ws + OFF_YP32);
  unsigned short* yp128  = (unsigned short*)(ws + OFF_YP128);
  unsigned short* yp16   = (unsigned short*)(ws + OFF_YP16);
  unsigned short* xpp    = (unsigned short*)(ws + OFF_XPP);
  float*          skp    = (float*)(ws + OFF_SKP);
  unsigned short* wc0 = (unsigned short*)(ws + OFF_WC0);
  unsigned short* wc1 = (unsigned short*)(ws + OFF_WC1);
  unsigned short* wcl = (unsigned short*)(ws + OFF_WCL);
  unsigned short* wp0 = (unsigned short*)(ws + OFF_WP0);
  unsigned short* wp1 = (unsigned short*)(ws + OFF_WP1);
  float* cmi  = (float*)(ws + OFF_CMI);
  float* cmj  = (float*)(ws + OFF_CMJ);
  float* nmi  = (float*)(ws + OFF_NMI);
  float* nmj  = (float*)(ws + OFF_NMJ);
  float* effpp= (float*)(ws + OFF_EFPP);
  float* lse_e= (float*)(ws + OFF_LSEE);
  float* lse_n= (float*)(ws + OFF_LSEN);
  float* nvb  = (float*)(ws + OFF_NV);
  float* nf   = (float*)(ws + OFF_NF);
  float* nt2  = (float*)(ws + OFF_NT2);
  float* nfeat  = (float*)(ws + OFF_NFEAT);
  float* nfeat2 = (float*)(ws + OFF_NFEAT2);
  float* xn   = (float*)(ws + OFF_XN);
  float* nfpp = (float*)(ws + OFF_NFPP);
  float* ncmi = (float*)(ws + OFF_NAC);
  float* ncmj = ncmi + 2304;
  float* nnmi = ncmi + 2*2304;
  float* nnmj = ncmi + 3*2304;

  float* out = (float*)d_out;
  float* o_bi   = out;
  float* o_bij  = out + 2304;
  float* o_mi   = out + 2304 + 5197824;
  float* o_mj   = o_mi + 108288;
  float* o_v    = o_mj + 108288;
  float* o_cd   = o_v + 48;
  float* o_nmem = o_cd + 1;
  float* o_emem = o_nmem + 147456;
  float* o_f1   = o_emem + 6930432;
  float* o_f2   = o_f1 + 2304;

  // 1. zero conv pad rows (yp128 pads re-zeroed later, after split-K reuse of its region)
  gm_zero_pads<<<EE, 128, 0, stream>>>(yp6, yp32, yp16);
  // 2. preps
  gm_prep_eeadj<<<(EP*EP+255)/256, 256, 0, stream>>>(eeadj, eeadjb);
  gm_prep_wall<<<(58880+255)/256, 256, 0, stream>>>(efm_w0, efm_w1, el_w, epp_w0, epp_w1,
                                                    wc0, wc1, wcl, wp0, wp1);
  // 3. messages
  gm_cmsg<<<EE, 128, 0, stream>>>(bi, bij, cmi, cmj);
  gm_node_accum<<<48, 256, 0, stream>>>(bij, cmi, cmj, msgi, msgj, dec, ncmi, ncmj, nnmi, nnmj, o_f1, o_f2);
  gm_build_x6<<<(288*EP+255)/256, 256, 0, stream>>>(msgi, msgj, cmi, cmj, bi, x6t);
  // 4. node feature CNN (fused map+conv per layer)
  gm_build_nf<<<(48*8*48+255)/256, 256, 0, stream>>>(bi, v_in, nnmi, nnmj, ncmi, ncmj, o_f1, o_f2, nf);
  gm_mapconv<<<48, 256, 0, stream>>>(neadj, nf,  fm_w0, fm_b0, nt2,   8, 32, 1);
  gm_mapconv<<<48, 256, 0, stream>>>(neadj, nt2, fm_w1, fm_b1, nfeat, 32, 32, 1);
  // 5. edge feature CNN
  gm_map_sk<<<216, 256, 0, stream>>>(eeadjb, x6t, skp, 18, 3, 4, 18);
  gm_sk_fin<<<(EE*288+255)/256, 256, 0, stream>>>(skp, yp6, nullptr, nullptr, 4, 384, 288, 6, 8, 0, 0);
  gm_conv_gemm<32><<<864, 256, 0, stream>>>(wc0, yp6,  x32t, efm_b0, 8, 8, 32, 32, 32, 1);
  gm_map_gemm<<<216, 256, 0, stream>>>(eeadjb, x32t, yp32, nullptr, nullptr, 18, 1536, 32, 32, 0, 0);
  gm_conv_gemm<32><<<864, 256, 0, stream>>>(wc1, yp32, x128t, efm_b1, 32, 32, 96, 32, 128, 1);
  // 6. fill LSTM input channels 32..127
  gm_fill_x128_hi<<<(96*EP+255)/256, 256, 0, stream>>>(emem0, nfeat, x128t);
  // 7. node LSTM (fused map+gateconv+pointwise)
  gm_xnode_copy<<<(48*64*48+255)/256, 256, 0, stream>>>(nfeat, nmem0, xn);
  gm_eton_x128<<<1536, 256, 0, stream>>>(x128t, xn);
  gm_mapconv_lstm<<<48, 512, 0, stream>>>(neadj, xn, nl_w, nl_b, nmem0, o_nmem, nfeat2);
  // 8. edge LSTM (re-zero yp128 pads first: split-K partials clobbered them)
  gm_zero_pad128<<<EE, 128, 0, stream>>>(yp128);
  gm_map_gemm<<<864, 256, 0, stream>>>(eeadjb, x128t, yp128, nullptr, nullptr, 18, 6144, 128, 128, 0, 0);
  gm_conv_gemm<128><<<864, 256, 0, stream>>>(wcl, yp128, gatesT, el_b, 128, 128, 384, 128, 128, 0);
  gm_elstm_pw<<<564*6, 256, 0, stream>>>(gatesT, emem0, o_emem);
  // 9. epp (conv-first commute; bias after map; split-K for both maps)
  gm_build_xpp<<<EE, 128, 0, stream>>>(o_emem, nfeat2, xpp);
  gm_conv_gemm<16><<<864, 256, 0, stream>>>(wp0, xpp,  z1t, nullptr, 96, 96, 288, 16, 16, 0);
  gm_map_sk<<<432, 256, 0, stream>>>(eeadjb, z1t, skp, 18, 6, 4, 18);
  gm_sk_fin<<<(EE*768+255)/256, 256, 0, stream>>>(skp, yp16, nullptr, epp_b0, 4, 768, 768, 16, 16, 1, 0);
  gm_conv_gemm<16><<<864, 256, 0, stream>>>(wp1, yp16, z2t, nullptr, 16, 16, 64, 2, 2, 0);
  gm_map_sk<<<144, 256, 0, stream>>>(eeadjb, z2t, skp, 18, 1, 8, 9);
  gm_sk_fin<<<(EE*96+255)/256, 256, 0, stream>>>(skp, nullptr, effpp, epp_b1, 8, 128, 96, 2, 2, 0, 1);
  // 10. pp (node, fused map+conv per layer)
  gm_x2_copy<<<(48*32*48+255)/256, 256, 0, stream>>>(nfeat2, xn);
  gm_eton_h<<<1536, 256, 0, stream>>>(o_emem, xn);
  gm_mapconv<<<48, 256, 0, stream>>>(neadj, xn,  pp_w0, pp_b0, nt2, 96, 16, 1);
  gm_mapconv<<<48, 256, 0, stream>>>(neadj, nt2, pp_w1, pp_b1, nfpp, 16, 1, 0);
  // 11. outputs
  gm_nv<<<1, 64, 0, stream>>>(nfpp, v_in, nvb, o_v);
  gm_bijout<<<EE, 256, 0, stream>>>(bij, effpp, cmi, cmj, msgi, msgj, nmi, nmj, o_mi, o_mj, o_bij, lse_e);
  gm_biout<<<48, 64, 0, stream>>>(bi, nmi, nmj, nvb, o_bi, lse_n);
  gm_cdual<<<1, 256, 0, stream>>>(lse_e, lse_n, o_v, o_cd);
}

// Round 9
// 795.449 us; speedup vs baseline: 1.2671x; 1.2671x over previous
//
#include <hip/hip_runtime.h>
#include <cstdint>
#include <cstddef>

#define EE 2256
#define EP 2304

typedef __attribute__((ext_vector_type(8))) short bf16x8;
typedef __attribute__((ext_vector_type(4))) float f32x4;

__device__ __forceinline__ unsigned short f2b(float f){
  unsigned u = __builtin_bit_cast(unsigned, f);
  u += 0x7fffu + ((u>>16)&1u);
  return (unsigned short)(u>>16);
}
__device__ __forceinline__ float b2f(unsigned short h){
  unsigned u = ((unsigned)h)<<16; return __builtin_bit_cast(float, u);
}
__device__ __forceinline__ float sigm(float x){ return 1.f/(1.f+__expf(-x)); }
__device__ __forceinline__ float tanhfast(float x){ return 1.f - 2.f/(__expf(2.f*x)+1.f); }

// bijective XCD-chunked swizzle (m204)
__device__ __forceinline__ int xcd_swz(int bid, int nwg){
  int xcd = bid & 7, idx = bid >> 3;
  int q = nwg >> 3, r = nwg & 7;
  return (xcd < r ? xcd*(q+1) : r*(q+1) + (xcd-r)*q) + idx;
}

typedef __attribute__((address_space(3))) unsigned int lds_u32;
typedef __attribute__((address_space(1))) const unsigned int gbl_u32;
__device__ __forceinline__ void glds16(const void* g, void* l){
  __builtin_amdgcn_global_load_lds((gbl_u32*)g, (lds_u32*)l, 16, 0, 0);
}

// ---------------- utility kernels ----------------
__global__ __launch_bounds__(128) void gm_zero_pads(unsigned short* yp6, unsigned short* yp32,
                                                    unsigned short* yp16){
  int e = blockIdx.x; int tid = threadIdx.x;
  #pragma unroll
  for (int r=0; r<2; ++r){
    int row = r ? 49 : 0;
    if (tid < 8)  yp6 [((size_t)e*50+row)*8  + tid] = 0;
    if (tid < 32) yp32[((size_t)e*50+row)*32 + tid] = 0;
    if (tid < 16) yp16[((size_t)e*50+row)*16 + tid] = 0;
  }
}

__global__ __launch_bounds__(128) void gm_zero_pad128(unsigned short* yp128){
  int e = blockIdx.x; int tid = threadIdx.x;
  yp128[((size_t)e*50+0)*128 + tid] = 0;
  yp128[((size_t)e*50+49)*128 + tid] = 0;
}

__global__ void gm_prep_eeadj(const float* __restrict__ src, unsigned short* __restrict__ dst){
  int idx = blockIdx.x*256 + threadIdx.x;
  if (idx >= EP*EP) return;
  int r = idx / EP, k = idx - r*EP;
  float v = (r < EE && k < EE) ? src[(size_t)r*EE + k] : 0.f;
  dst[idx] = f2b(v);
}

__global__ void gm_prep_wall(const float* __restrict__ w0, const float* __restrict__ w1,
                             const float* __restrict__ w2, const float* __restrict__ w3,
                             const float* __restrict__ w4,
                             unsigned short* d0, unsigned short* d1, unsigned short* d2,
                             unsigned short* d3, unsigned short* d4){
  int idx = blockIdx.x*256 + threadIdx.x;
  const float* w; unsigned short* dp; int Co,Cin,KPT,Kpad,loc;
  if      (idx < 1024) { w=w0; dp=d0; Co=32;  Cin=6;   KPT=8;   Kpad=32;  loc=idx; }
  else if (idx < 4096) { w=w1; dp=d1; Co=32;  Cin=32;  KPT=32;  Kpad=96;  loc=idx-1024; }
  else if (idx < 53248){ w=w2; dp=d2; Co=128; Cin=128; KPT=128; Kpad=384; loc=idx-4096; }
  else if (idx < 57856){ w=w3; dp=d3; Co=16;  Cin=96;  KPT=96;  Kpad=288; loc=idx-53248; }
  else if (idx < 58880){ w=w4; dp=d4; Co=2;   Cin=16;  KPT=16;  Kpad=64;  loc=idx-57856; }
  else return;
  int co = loc / Kpad; int k = loc - co*Kpad;
  int t = k / KPT; int ci = k - t*KPT;
  float v = (co < Co && t < 3 && ci < Cin) ? w[((size_t)co*Cin + ci)*3 + t] : 0.f;
  dp[loc] = f2b(v);
}

// ---------------- message LSE kernels ----------------
__global__ __launch_bounds__(128) void gm_cmsg(const float* __restrict__ bi, const float* __restrict__ bij,
                                               float* __restrict__ cmi, float* __restrict__ cmj){
  int e = blockIdx.x; int tid = threadIdx.x;
  __shared__ float t[48*49]; __shared__ float bs[48], bd[48];
  const float* src = bij + (size_t)e*2304;
  for (int i=tid;i<2304;i+=128){ int r=i/48, c=i-r*48; t[r*49+c]=src[i]; }
  if (tid<48){ int s=e/47, m=e-s*47; int d=m+(m>=s); bs[tid]=bi[s*48+tid]; bd[tid]=bi[d*48+tid]; }
  __syncthreads();
  if (tid < 48){
    float mx=-1e30f;
    for (int n=0;n<48;n++) mx = fmaxf(mx, t[tid*49+n]+bd[n]);
    float sm=0.f;
    for (int n=0;n<48;n++) sm += __expf((t[tid*49+n]+bd[n]-mx)*20.f);
    cmi[e*48+tid] = mx + __logf(sm)*(1.f/20.f);
  } else if (tid>=64 && tid<112){
    int n = tid-64;
    float mx=-1e30f;
    for (int k=0;k<48;k++) mx = fmaxf(mx, t[k*49+n]+bs[k]);
    float sm=0.f;
    for (int k=0;k<48;k++) sm += __expf((t[k*49+n]+bs[k]-mx)*20.f);
    cmj[e*48+n] = mx + __logf(sm)*(1.f/20.f);
  }
}

__global__ __launch_bounds__(256) void gm_node_accum(const float* __restrict__ bij, const float* __restrict__ cmi,
                              const float* __restrict__ cmj, const float* __restrict__ msgi,
                              const float* __restrict__ msgj, const int* __restrict__ dec,
                              float* ncmi, float* ncmj, float* nnmi, float* nnmj,
                              float* o_f1, float* o_f2){
  int i = blockIdx.x; int tid = threadIdx.x;
  __shared__ float red[5][6][48];
  int mg = tid / 48;
  int w  = tid - mg*48;
  if (mg < 5){
    int dc = dec[i];
    float a1=0,a2=0,a3=0,a4=0,s1=0,s2=0;
    for (int m=mg; m<47; m+=5){
      int e1 = i*47+m;
      a1 += cmi[e1*48+w]; a3 += msgi[e1*48+w];
      s1 += bij[(size_t)e1*2304 + dc*48 + w];
      int j = m + (m>=i); int e2 = j*47 + i - (i>j);
      a2 += cmj[e2*48+w]; a4 += msgj[e2*48+w];
      s2 += bij[(size_t)e2*2304 + w*48 + dc];
    }
    red[mg][0][w]=a1; red[mg][1][w]=a2; red[mg][2][w]=a3;
    red[mg][3][w]=a4; red[mg][4][w]=s1; red[mg][5][w]=s2;
  }
  __syncthreads();
  if (tid < 48){
    float a1=0,a2=0,a3=0,a4=0,s1=0,s2=0;
    for (int g=0; g<5; g++){
      a1+=red[g][0][tid]; a2+=red[g][1][tid]; a3+=red[g][2][tid];
      a4+=red[g][3][tid]; s1+=red[g][4][tid]; s2+=red[g][5][tid];
    }
    ncmi[i*48+tid]=a1; ncmj[i*48+tid]=a2; nnmi[i*48+tid]=a3; nnmj[i*48+tid]=a4;
    o_f1[i*48+tid]=s1; o_f2[i*48+tid]=s2;
  }
}

// ---------------- staging builders ----------------
__global__ void gm_build_x6(const float* __restrict__ msgi, const float* __restrict__ msgj,
                            const float* __restrict__ cmi, const float* __restrict__ cmj,
                            const float* __restrict__ bi, unsigned short* __restrict__ x6){
  int idx = blockIdx.x*256 + threadIdx.x;
  if (idx >= 288*EP) return;
  int row = idx / EP, e = idx - row*EP;
  int w = row / 6, c = row - w*6;
  unsigned short val = 0;
  if (e < EE){
    int s = e/47, m = e-s*47, d = m + (m>=s);
    float x;
    switch(c){
      case 0: x = msgi[e*48+w]; break;
      case 1: x = msgj[e*48+w]; break;
      case 2: x = cmi[e*48+w]; break;
      case 3: x = cmj[e*48+w]; break;
      case 4: x = bi[s*48+w]; break;
      default: x = bi[d*48+w]; break;
    }
    val = f2b(x);
  }
  x6[idx] = val;
}

__global__ void gm_fill_x128_hi(const float* __restrict__ emem0, const float* __restrict__ nfeat,
                                unsigned short* __restrict__ x128){
  int idx = blockIdx.x*256 + threadIdx.x;
  if (idx >= 96*EP) return;
  int q = idx/EP; int c = 32 + q; int e = idx - q*EP;
  if (e >= EE){ for (int w=0;w<48;w++) x128[(size_t)(w*128+c)*EP + e] = 0; return; }
  int s=e/47, m=e-s*47, d=m+(m>=s);
  const float* srcrow;
  if (c < 64)      srcrow = nfeat + ((size_t)s*32 + (c-32))*48;
  else if (c < 96) srcrow = nfeat + ((size_t)d*32 + (c-64))*48;
  else             srcrow = emem0 + ((size_t)e*64 + (c-64))*48;
  #pragma unroll
  for (int w4=0; w4<12; w4++){
    float4 xv = *(const float4*)(srcrow + w4*4);
    x128[(size_t)((w4*4+0)*128+c)*EP + e] = f2b(xv.x);
    x128[(size_t)((w4*4+1)*128+c)*EP + e] = f2b(xv.y);
    x128[(size_t)((w4*4+2)*128+c)*EP + e] = f2b(xv.z);
    x128[(size_t)((w4*4+3)*128+c)*EP + e] = f2b(xv.w);
  }
}

// ---------------- MFMA map GEMM (single-buffer, col-major XCD chunking) ----------------
__global__ __launch_bounds__(256) void gm_map_gemm(
    const unsigned short* __restrict__ A, const unsigned short* __restrict__ BT,
    unsigned short* __restrict__ ypad, float* __restrict__ outf,
    const float* __restrict__ bias, int nrow, int Nvalid, int Cch, int Cslab,
    int do_relu, int f32_out)
{
  __shared__ __align__(16) unsigned short lA[128*32];
  __shared__ __align__(16) unsigned short lB[128*32];
  const int tid = threadIdx.x;
  const int lane = tid & 63, wid = tid >> 6;
  const int swz = xcd_swz(blockIdx.x, gridDim.x);
  const int m0 = (swz % nrow) * 128;
  const int n0 = (swz / nrow) * 128;
  const int wm = wid >> 1, wn = wid & 1;
  f32x4 acc[4][4];
  #pragma unroll
  for (int i=0;i<4;i++){
    #pragma unroll
    for (int j=0;j<4;j++) acc[i][j] = f32x4{0.f,0.f,0.f,0.f};
  }
  const int srow = (lane>>2), scol = (lane&3);

  for (int ks = 0; ks < EP/32; ++ks) {
    #pragma unroll
    for (int q=0;q<2;q++){
      int chunk = wid*2+q;
      int row = chunk*16 + srow;
      int off = (scol*16) ^ (((row>>1)&3)<<4);
      glds16((const char*)A  + (size_t)(m0+row)*(EP*2) + ks*64 + off, (char*)lA + chunk*1024);
      glds16((const char*)BT + (size_t)(n0+row)*(EP*2) + ks*64 + off, (char*)lB + chunk*1024);
    }
    __syncthreads();
    bf16x8 af[4], bfr[4];
    #pragma unroll
    for (int mi=0;mi<4;mi++){
      int row = wm*64 + mi*16 + (lane&15);
      int off = ((lane>>4)*16) ^ (((row>>1)&3)<<4);
      af[mi] = *(const bf16x8*)((const char*)lA + row*64 + off);
    }
    #pragma unroll
    for (int ni=0;ni<4;ni++){
      int row = wn*64 + ni*16 + (lane&15);
      int off = ((lane>>4)*16) ^ (((row>>1)&3)<<4);
      bfr[ni] = *(const bf16x8*)((const char*)lB + row*64 + off);
    }
    #pragma unroll
    for (int mi=0;mi<4;mi++){
      #pragma unroll
      for (int ni=0;ni<4;ni++)
        acc[mi][ni] = __builtin_amdgcn_mfma_f32_16x16x32_bf16(af[mi], bfr[ni], acc[mi][ni], 0,0,0);
    }
    __syncthreads();
  }
  #pragma unroll
  for (int mi=0;mi<4;mi++){
    int ebase = m0 + wm*64 + mi*16 + (lane>>4)*4;
    #pragma unroll
    for (int ni=0;ni<4;ni++){
      int c = n0 + wn*64 + ni*16 + (lane&15);
      if (c >= Nvalid) continue;
      int w = c / Cch, ci = c - w*Cch;
      float bv = bias ? bias[ci] : 0.f;
      #pragma unroll
      for (int r=0;r<4;r++){
        int e = ebase + r;
        if (e >= EE) continue;
        float x = acc[mi][ni][r] + bv;
        if (do_relu) x = fmaxf(x, 0.f);
        if (f32_out) outf[(size_t)e*Nvalid + c] = x;
        else ypad[((size_t)e*50 + 1 + w)*Cslab + ci] = f2b(x);
      }
    }
  }
}

// split-K variant (single-buffer): writes f32 partials pbuf[sp][e][c]
__global__ __launch_bounds__(256) void gm_map_sk(
    const unsigned short* __restrict__ A, const unsigned short* __restrict__ BT,
    float* __restrict__ pbuf, int nrow, int ncol, int S, int kspan)
{
  __shared__ __align__(16) unsigned short lA[128*32];
  __shared__ __align__(16) unsigned short lB[128*32];
  const int tid = threadIdx.x;
  const int lane = tid & 63, wid = tid >> 6;
  const int swz = xcd_swz(blockIdx.x, gridDim.x);
  const int ntile = nrow*ncol;
  const int sp = swz / ntile;
  const int tile = swz - sp*ntile;
  const int m0 = (tile % nrow) * 128;
  const int n0 = (tile / nrow) * 128;
  const int Npad = ncol*128;
  const int k0 = sp*kspan, k1 = k0 + kspan;
  const int wm = wid >> 1, wn = wid & 1;
  f32x4 acc[4][4];
  #pragma unroll
  for (int i=0;i<4;i++){
    #pragma unroll
    for (int j=0;j<4;j++) acc[i][j] = f32x4{0.f,0.f,0.f,0.f};
  }
  const int srow = (lane>>2), scol = (lane&3);

  for (int ks = k0; ks < k1; ++ks){
    #pragma unroll
    for (int q=0;q<2;q++){
      int chunk = wid*2+q;
      int row = chunk*16 + srow;
      int off = (scol*16) ^ (((row>>1)&3)<<4);
      glds16((const char*)A  + (size_t)(m0+row)*(EP*2) + ks*64 + off, (char*)lA + chunk*1024);
      glds16((const char*)BT + (size_t)(n0+row)*(EP*2) + ks*64 + off, (char*)lB + chunk*1024);
    }
    __syncthreads();
    bf16x8 af[4], bfr[4];
    #pragma unroll
    for (int mi=0;mi<4;mi++){
      int row = wm*64 + mi*16 + (lane&15);
      int off = ((lane>>4)*16) ^ (((row>>1)&3)<<4);
      af[mi] = *(const bf16x8*)((const char*)lA + row*64 + off);
    }
    #pragma unroll
    for (int ni=0;ni<4;ni++){
      int row = wn*64 + ni*16 + (lane&15);
      int off = ((lane>>4)*16) ^ (((row>>1)&3)<<4);
      bfr[ni] = *(const bf16x8*)((const char*)lB + row*64 + off);
    }
    #pragma unroll
    for (int mi=0;mi<4;mi++){
      #pragma unroll
      for (int ni=0;ni<4;ni++)
        acc[mi][ni] = __builtin_amdgcn_mfma_f32_16x16x32_bf16(af[mi], bfr[ni], acc[mi][ni], 0,0,0);
    }
    __syncthreads();
  }
  float* pb = pbuf + (size_t)sp*2304*Npad;
  #pragma unroll
  for (int mi=0;mi<4;mi++){
    int ebase = m0 + wm*64 + mi*16 + (lane>>4)*4;
    #pragma unroll
    for (int ni=0;ni<4;ni++){
      int c = n0 + wn*64 + ni*16 + (lane&15);
      #pragma unroll
      for (int r=0;r<4;r++)
        pb[(size_t)(ebase+r)*Npad + c] = acc[mi][ni][r];
    }
  }
}

__global__ void gm_sk_fin(const float* __restrict__ pbuf, unsigned short* __restrict__ ypad,
                          float* __restrict__ outf, const float* __restrict__ bias,
                          int S, int Npad, int Nvalid, int Cch, int Cslab, int do_relu, int f32_out){
  int idx = blockIdx.x*256 + threadIdx.x;
  if (idx >= EE*Nvalid) return;
  int e = idx / Nvalid, c = idx - e*Nvalid;
  float s = 0.f;
  for (int p=0;p<S;p++) s += pbuf[(size_t)p*2304*Npad + (size_t)e*Npad + c];
  int w = c / Cch, ci = c - w*Cch;
  if (bias) s += bias[ci];
  if (do_relu) s = fmaxf(s, 0.f);
  if (f32_out) outf[(size_t)e*Nvalid + c] = s;
  else ypad[((size_t)e*50 + 1 + w)*Cslab + ci] = f2b(s);
}

// ---------------- MFMA conv GEMM (operand-swapped, single-buffer) ----------------
template<int BM>
__global__ __launch_bounds__(256) void gm_conv_gemm(
    const unsigned short* __restrict__ Wp, const unsigned short* __restrict__ ypad,
    unsigned short* __restrict__ outT, const float* __restrict__ bias,
    int Cch, int KPT, int Kpad, int Co, int Ct, int do_relu)
{
  constexpr int MI = (BM==128)?4:((BM==32)?2:1);
  constexpr int NI = (BM==128)?4:2;
  __shared__ __align__(16) unsigned short lA[BM*32];
  __shared__ __align__(16) unsigned short lB[128*32];
  const int tid = threadIdx.x, lane = tid&63, wid = tid>>6;
  const int swz = xcd_swz(blockIdx.x, 864);
  const int e0 = (swz / 48) * 128;
  const int w  = swz % 48;
  const int rowb = (BM==128)? (wid>>1)*64 : 0;
  const int colb = (BM==128)? (wid&1)*64 : wid*32;
  f32x4 acc[MI][NI];
  #pragma unroll
  for (int i=0;i<MI;i++){
    #pragma unroll
    for (int j=0;j<NI;j++) acc[i][j] = f32x4{0.f,0.f,0.f,0.f};
  }
  const int srow=(lane>>2), scol=(lane&3);
  const int ksteps = Kpad/32;
  for (int ks=0; ks<ksteps; ++ks){
    for (int c = wid; c < BM/16; c += 4){
      int row = c*16 + srow;
      int off = (scol*16) ^ (((row>>1)&3)<<4);
      glds16((const char*)Wp + (size_t)row*(Kpad*2) + ks*64 + off, (char*)lA + c*1024);
    }
    for (int c = wid; c < 8; c += 4){
      int row = c*16 + srow;
      int off = (scol*16) ^ (((row>>1)&3)<<4);
      int kg = ks*32 + (off>>1);
      int t = kg / KPT;
      int ci = kg - t*KPT;
      int e = e0 + row;
      const char* src;
      if (t < 3 && e < EE) src = (const char*)ypad + ((size_t)(e*50 + w + t)*Cch + ci)*2;
      else                 src = (const char*)ypad;
      glds16(src, (char*)lB + c*1024);
    }
    __syncthreads();
    bf16x8 af[MI], bfr[NI];
    #pragma unroll
    for (int mi=0;mi<MI;mi++){
      int row = rowb + mi*16 + (lane&15);
      int off = ((lane>>4)*16) ^ (((row>>1)&3)<<4);
      af[mi] = *(const bf16x8*)((const char*)lA + row*64 + off);
    }
    #pragma unroll
    for (int ni=0;ni<NI;ni++){
      int row = colb + ni*16 + (lane&15);
      int off = ((lane>>4)*16) ^ (((row>>1)&3)<<4);
      bfr[ni] = *(const bf16x8*)((const char*)lB + row*64 + off);
    }
    #pragma unroll
    for (int mi=0;mi<MI;mi++){
      #pragma unroll
      for (int ni=0;ni<NI;ni++)
        acc[mi][ni] = __builtin_amdgcn_mfma_f32_16x16x32_bf16(af[mi], bfr[ni], acc[mi][ni], 0,0,0);
    }
    __syncthreads();
  }
  #pragma unroll
  for (int mi=0;mi<MI;mi++){
    #pragma unroll
    for (int ni=0;ni<NI;ni++){
      int m = colb + ni*16 + (lane&15);
      int e = e0 + m;
      if (e >= EE) continue;
      #pragma unroll
      for (int r=0;r<4;r++){
        int co = rowb + mi*16 + (lane>>4)*4 + r;
        if (co >= Co) continue;
        float x = acc[mi][ni][r] + (bias ? bias[co] : 0.f);
        if (do_relu) x = fmaxf(x, 0.f);
        outT[((size_t)(w*Ct + co))*EP + e] = f2b(x);
      }
    }
  }
}

// ---------------- node-side kernels (R5 structure: wide-parallel) ----------------
__global__ void gm_build_nf(const float* __restrict__ bi, const float* __restrict__ v,
                            const float* __restrict__ nnmi, const float* __restrict__ nnmj,
                            const float* __restrict__ ncmi, const float* __restrict__ ncmj,
                            const float* __restrict__ f1, const float* __restrict__ f2,
                            float* __restrict__ nf){
  int idx = blockIdx.x*256+threadIdx.x;
  if (idx >= 48*8*48) return;
  int i = idx/(8*48); int rem = idx - i*(8*48); int c = rem/48; int w = rem-c*48;
  int iw = i*48+w;
  float x;
  switch(c){
    case 0: x=bi[iw]; break;
    case 1: x=bi[iw]+v[w]; break;
    case 2: x=nnmi[iw]; break;
    case 3: x=nnmj[iw]; break;
    case 4: x=ncmi[iw]; break;
    case 5: x=ncmj[iw]; break;
    case 6: x=f1[iw]; break;
    default: x=f2[iw]; break;
  }
  nf[idx]=x;
}

__global__ void gm_nmap(const float* __restrict__ adj, const float* __restrict__ X,
                        float* __restrict__ Y, int C){
  int idx = blockIdx.x*256 + threadIdx.x;
  int tot = 48*C*48;
  if (idx >= tot) return;
  int i = idx/(C*48); int rem = idx - i*(C*48);
  float s=0.f;
  for (int j=0;j<48;j++) s += adj[i*48+j]*X[(size_t)j*C*48 + rem];
  Y[idx]=s;
}

__global__ void gm_nconv(const float* __restrict__ X, const float* __restrict__ wgt,
                         const float* __restrict__ bias, float* __restrict__ Y,
                         int Cin, int Co, int relu){
  int idx = blockIdx.x*256 + threadIdx.x;
  int tot = 48*Co*48;
  if (idx >= tot) return;
  int i = idx/(Co*48); int rem = idx - i*(Co*48); int co = rem/48; int w = rem-co*48;
  float s = bias[co];
  const float* xb = X + (size_t)i*Cin*48;
  const float* wb = wgt + (size_t)co*Cin*3;
  for (int ci=0; ci<Cin; ++ci){
    float w0 = wb[ci*3], w1 = wb[ci*3+1], w2 = wb[ci*3+2];
    const float* xr = xb + ci*48;
    if (w > 0) s += xr[w-1]*w0;
    s += xr[w]*w1;
    if (w < 47) s += xr[w+1]*w2;
  }
  if (relu) s = fmaxf(s, 0.f);
  Y[idx] = s;
}

// fused 128->128 gate conv + LSTM pointwise (node side)
__global__ __launch_bounds__(256) void gm_nconv_lstm(const float* __restrict__ X,
    const float* __restrict__ wgt, const float* __restrict__ bias,
    const float* __restrict__ nmem0, float* __restrict__ o_nmem, float* __restrict__ nfeat2){
  int idx = blockIdx.x*256 + threadIdx.x;
  if (idx >= 48*32*48) return;
  int i = idx/(32*48); int rem = idx - i*(32*48); int ch = rem/48; int w = rem-ch*48;
  const float* xb = X + (size_t)i*128*48;
  float s0=bias[ch], s1=bias[32+ch], s2=bias[64+ch], s3=bias[96+ch];
  for (int ci=0; ci<128; ++ci){
    const float* xr = xb + ci*48;
    float xm = (w>0)? xr[w-1] : 0.f;
    float xc = xr[w];
    float xp = (w<47)? xr[w+1] : 0.f;
    const float* wb0 = wgt + ((size_t)ch*128+ci)*3;
    const float* wb1 = wgt + ((size_t)(32+ch)*128+ci)*3;
    const float* wb2 = wgt + ((size_t)(64+ch)*128+ci)*3;
    const float* wb3 = wgt + ((size_t)(96+ch)*128+ci)*3;
    s0 += xm*wb0[0]+xc*wb0[1]+xp*wb0[2];
    s1 += xm*wb1[0]+xc*wb1[1]+xp*wb1[2];
    s2 += xm*wb2[0]+xc*wb2[1]+xp*wb2[2];
    s3 += xm*wb3[0]+xc*wb3[1]+xp*wb3[2];
  }
  float c = nmem0[((size_t)i*64+ch)*48+w];
  float c2 = sigm(s1)*c + sigm(s0)*tanhfast(s2);
  float h2 = sigm(s3)*tanhfast(c2);
  o_nmem[((size_t)i*64+ch)*48+w] = c2;
  o_nmem[((size_t)i*64+32+ch)*48+w] = h2;
  nfeat2[((size_t)i*32+ch)*48+w] = h2;
}

// row-wise eton gathers from x128t efeat rows -> xn channels 32..95
__global__ __launch_bounds__(256) void gm_eton_x128(const unsigned short* __restrict__ x128,
                                                    float* __restrict__ xn){
  int row = blockIdx.x;          // w*32+cc
  int w = row >> 5, cc = row & 31;
  __shared__ float L[2256];
  const unsigned short* src = x128 + (size_t)(w*128 + cc)*EP;
  for (int t=threadIdx.x; t<2256; t+=256) L[t] = b2f(src[t]);
  __syncthreads();
  int tid = threadIdx.x;
  if (tid < 48){
    int i = tid; float s=0.f;
    for (int m=0;m<47;m++) s += L[i*47+m];
    xn[((size_t)i*128 + 32 + cc)*48 + w] = s;
  } else if (tid >= 64 && tid < 112){
    int i = tid-64; float s=0.f;
    for (int m=0;m<47;m++){
      int j = m + (m>=i);
      s += L[j*47 + i - (i>j)];
    }
    xn[((size_t)i*128 + 64 + cc)*48 + w] = s;
  }
}

__global__ void gm_xnode_copy(const float* __restrict__ nfeat, const float* __restrict__ nmem0,
                              float* __restrict__ xn){
  int idx = blockIdx.x*256+threadIdx.x;
  if (idx >= 48*64*48) return;
  int i = idx/(64*48); int rem = idx - i*(64*48); int c = rem/48; int w = rem-c*48;
  if (c < 32) xn[((size_t)i*128 + c)*48 + w] = nfeat[((size_t)i*32+c)*48+w];
  else        xn[((size_t)i*128 + 96 + (c-32))*48 + w] = nmem0[((size_t)i*64 + 32 + (c-32))*48 + w];
}

__global__ __launch_bounds__(256) void gm_elstm_pw(const unsigned short* __restrict__ gatesT,
                                                   const float* __restrict__ emem0,
                                                   float* __restrict__ o_emem){
  int bid = blockIdx.x;
  int e4 = bid / 6, chunk = bid - e4*6;
  int cw = chunk*256 + threadIdx.x;
  int ch = cw / 48, w = cw - ch*48;
  int ebase = e4*4;
  const unsigned short* g0 = gatesT + (size_t)(w*128 + ch)*EP + ebase;
  ushort4 vi = *(const ushort4*)(g0);
  ushort4 vf = *(const ushort4*)(g0 + (size_t)32*EP);
  ushort4 vg = *(const ushort4*)(g0 + (size_t)64*EP);
  ushort4 vo = *(const ushort4*)(g0 + (size_t)96*EP);
  const unsigned short* pi = (const unsigned short*)&vi;
  const unsigned short* pf = (const unsigned short*)&vf;
  const unsigned short* pg = (const unsigned short*)&vg;
  const unsigned short* po = (const unsigned short*)&vo;
  #pragma unroll
  for (int r=0;r<4;r++){
    int e = ebase + r;
    float gi = b2f(pi[r]), gf = b2f(pf[r]), gg = b2f(pg[r]), go = b2f(po[r]);
    float c  = emem0[((size_t)e*64 + ch)*48 + w];
    float c2 = sigm(gf)*c + sigm(gi)*tanhfast(gg);
    float h2 = sigm(go)*tanhfast(c2);
    o_emem[((size_t)e*64 + ch)*48 + w] = c2;
    o_emem[((size_t)e*64 + 32+ch)*48 + w] = h2;
  }
}

__global__ __launch_bounds__(256) void gm_eton_h(const float* __restrict__ o_emem,
                                                 float* __restrict__ x2){
  int row = blockIdx.x; int w = row >> 5, cc = row & 31;
  __shared__ float L[2256];
  for (int t=threadIdx.x; t<2256; t+=256)
    L[t] = o_emem[((size_t)t*64 + 32 + cc)*48 + w];
  __syncthreads();
  int tid = threadIdx.x;
  if (tid < 48){
    int i=tid; float s=0.f;
    for (int m=0;m<47;m++) s += L[i*47+m];
    x2[((size_t)i*96 + 32 + cc)*48 + w] = s;
  } else if (tid>=64 && tid<112){
    int i=tid-64; float s=0.f;
    for (int m=0;m<47;m++){ int j=m+(m>=i); s += L[j*47 + i - (i>j)]; }
    x2[((size_t)i*96 + 64 + cc)*48 + w] = s;
  }
}

__global__ void gm_x2_copy(const float* __restrict__ nfeat2, float* __restrict__ x2){
  int idx = blockIdx.x*256+threadIdx.x;
  if (idx >= 48*32*48) return;
  int i = idx/(32*48); int rem = idx - i*(32*48); int c = rem/48; int w = rem-c*48;
  x2[((size_t)i*96 + c)*48 + w] = nfeat2[idx];
}

__global__ __launch_bounds__(128) void gm_build_xpp(const float* __restrict__ o_emem,
                                                    const float* __restrict__ nfeat2,
                                                    unsigned short* __restrict__ xpp){
  int e = blockIdx.x; int tid = threadIdx.x;
  __shared__ float h[1536];
  __shared__ float sn[3072];
  int s = e/47; int m = e - s*47; int d = m + (m>=s);
  const float* src = o_emem + ((size_t)e*64 + 32)*48;
  for (int i=tid;i<1536;i+=128) h[i]=src[i];
  const float* ps = nfeat2 + (size_t)s*32*48;
  const float* pd = nfeat2 + (size_t)d*32*48;
  for (int i=tid;i<1536;i+=128){ sn[i]=ps[i]; sn[1536+i]=pd[i]; }
  if (tid < 96){
    xpp[((size_t)e*50 + 0)*96 + tid] = 0;
    xpp[((size_t)e*50 + 49)*96 + tid] = 0;
  }
  __syncthreads();
  for (int w=0; w<48; w++){
    if (tid < 96){
      float x;
      if (tid<32) x = h[tid*48+w];
      else x = sn[(tid-32)*48 + w];
      xpp[((size_t)e*50 + 1 + w)*96 + tid] = f2b(x);
    }
  }
}

__global__ void gm_nv(const float* __restrict__ nfpp, const float* __restrict__ v,
                      float* __restrict__ nv, float* __restrict__ o_v){
  int w = threadIdx.x;
  if (w<48){
    float s=0.f; for (int i=0;i<48;i++) s += nfpp[i*48+w];
    s *= (1.f/48.f);
    nv[w]=s; o_v[w]=v[w]+s;
  }
}

// fused: nmsg + bij output + edge LSE
__global__ __launch_bounds__(256) void gm_bijout(const float* __restrict__ bij,
                                                 const float* __restrict__ effpp,
                                                 const float* __restrict__ cmi, const float* __restrict__ cmj,
                                                 const float* __restrict__ msgi, const float* __restrict__ msgj,
                                                 float* __restrict__ nmi, float* __restrict__ nmj,
                                                 float* __restrict__ o_mi, float* __restrict__ o_mj,
                                                 float* __restrict__ o_bij, float* __restrict__ lse_e){
  int e = blockIdx.x; int tid = threadIdx.x;
  __shared__ float ri[48], rj[48], red[8];
  if (tid < 48){
    int idx = e*48+tid;
    float a = effpp[(size_t)e*96 + tid*2] + 0.5f*cmi[idx] - msgi[idx];
    ri[tid] = a; nmi[idx] = a; o_mi[idx] = msgi[idx] + a;
  } else if (tid >= 64 && tid < 112){
    int t2 = tid-64; int idx = e*48+t2;
    float b = effpp[(size_t)e*96 + t2*2 + 1] + 0.5f*cmj[idx] - msgj[idx];
    rj[t2] = b; nmj[idx] = b; o_mj[idx] = msgj[idx] + b;
  }
  __syncthreads();
  float v[9]; float mx = -1e30f;
  const float* src = bij + (size_t)e*2304;
  float* dst = o_bij + (size_t)e*2304;
  #pragma unroll
  for (int q=0;q<9;q++){
    int idx = q*256 + tid;
    int r = idx/48, c = idx-r*48;
    float x = src[idx] - ri[r] - rj[c];
    dst[idx] = x; v[q] = x; mx = fmaxf(mx, x);
  }
  for (int o=1;o<64;o<<=1) mx = fmaxf(mx, __shfl_xor(mx, o, 64));
  int lane = tid&63, w4 = tid>>6;
  if (lane==0) red[w4] = mx;
  __syncthreads();
  mx = fmaxf(fmaxf(red[0],red[1]),fmaxf(red[2],red[3]));
  float s = 0.f;
  #pragma unroll
  for (int q=0;q<9;q++) s += __expf((v[q]-mx)*20.f);
  for (int o=1;o<64;o<<=1) s += __shfl_xor(s, o, 64);
  if (lane==0) red[4+w4] = s;
  __syncthreads();
  if (tid==0){
    float t = red[4]+red[5]+red[6]+red[7];
    lse_e[e] = mx + __logf(t)*(1.f/20.f);
  }
}

__global__ void gm_biout(const float* __restrict__ bi, const float* __restrict__ nmi,
                         const float* __restrict__ nmj, const float* __restrict__ nv,
                         float* __restrict__ o_bi, float* __restrict__ lse_n){
  int i = blockIdx.x; int w = threadIdx.x;
  float val = -1e30f;
  if (w < 48){
    float s = 0.f;
    for (int m=0;m<47;m++){
      int e1 = i*47+m;
      s += nmi[e1*48+w];
      int j = m + (m>=i);
      int e2 = j*47 + i - (i>j);
      s += nmj[e2*48+w];
    }
    val = bi[i*48+w] + s - nv[w];
    o_bi[i*48+w] = val;
  }
  float mx = val;
  for (int o=1;o<64;o<<=1) mx = fmaxf(mx, __shfl_xor(mx, o, 64));
  float ex = (w<48)? __expf((val-mx)*20.f) : 0.f;
  for (int o=1;o<64;o<<=1) ex += __shfl_xor(ex, o, 64);
  if (w==0) lse_n[i] = mx + __logf(ex)*(1.f/20.f);
}

__global__ void gm_cdual(const float* __restrict__ lse_e, const float* __restrict__ lse_n,
                         const float* __restrict__ vout, float* __restrict__ out){
  int tid = threadIdx.x;
  float s = 0.f;
  for (int i=tid;i<EE;i+=256) s += lse_e[i];
  if (tid<48) s += lse_n[tid] + vout[tid];
  __shared__ float red[4];
  for (int o=1;o<64;o<<=1) s += __shfl_xor(s,o,64);
  if ((tid&63)==0) red[tid>>6]=s;
  __syncthreads();
  if (tid==0) out[0] = red[0]+red[1]+red[2]+red[3];
}

// ---------------- workspace layout ----------------
static constexpr size_t A256v(size_t x){ return (x+255)&~(size_t)255; }
static constexpr size_t OFF_EEADJ = 0;
static constexpr size_t OFF_X6T   = A256v(OFF_EEADJ + (size_t)EP*EP*2);
static constexpr size_t OFF_X32T  = A256v(OFF_X6T  + (size_t)384*EP*2);
static constexpr size_t OFF_X128T = A256v(OFF_X32T + (size_t)1536*EP*2);
static constexpr size_t OFF_YP6   = A256v(OFF_X128T + (size_t)6144*EP*2);
static constexpr size_t OFF_YP32  = A256v(OFF_YP6  + (size_t)EE*50*8*2);
static constexpr size_t OFF_YP128 = A256v(OFF_YP32 + (size_t)EE*50*32*2);
static constexpr size_t OFF_YP16  = A256v(OFF_YP128 + (size_t)EE*50*128*2);
static constexpr size_t OFF_ZEND  = A256v(OFF_YP16 + (size_t)EE*50*16*2 + 256);
static constexpr size_t OFF_XPP   = OFF_YP128;
static constexpr size_t OFF_SKP   = OFF_YP128;
static constexpr size_t OFF_WC0 = OFF_ZEND;
static constexpr size_t OFF_WC1 = A256v(OFF_WC0 + 32*32*2);
static constexpr size_t OFF_WCL = A256v(OFF_WC1 + 32*96*2);
static constexpr size_t OFF_WP0 = A256v(OFF_WCL + 128*384*2);
static constexpr size_t OFF_WP1 = A256v(OFF_WP0 + 16*288*2);
static constexpr size_t OFF_CMI = A256v(OFF_WP1 + 16*64*2);
static constexpr size_t OFF_CMJ = A256v(OFF_CMI + (size_t)EE*48*4);
static constexpr size_t OFF_NMI = A256v(OFF_CMJ + (size_t)EE*48*4);
static constexpr size_t OFF_NMJ = A256v(OFF_NMI + (size_t)EE*48*4);
static constexpr size_t OFF_EFPP= A256v(OFF_NMJ + (size_t)EE*48*4);
static constexpr size_t OFF_LSEE= A256v(OFF_EFPP + (size_t)EE*96*4);
static constexpr size_t OFF_LSEN= A256v(OFF_LSEE + EE*4);
static constexpr size_t OFF_NV  = A256v(OFF_LSEN + 48*4);
static constexpr size_t OFF_NF  = A256v(OFF_NV + 48*4);
static constexpr size_t OFF_NT1 = A256v(OFF_NF + (size_t)48*8*48*4);
static constexpr size_t OFF_NT2 = A256v(OFF_NT1 + (size_t)48*128*48*4);
static constexpr size_t OFF_NFEAT = A256v(OFF_NT2 + (size_t)48*32*48*4);
static constexpr size_t OFF_NFEAT2= A256v(OFF_NFEAT + (size_t)48*32*48*4);
static constexpr size_t OFF_XN  = A256v(OFF_NFEAT2 + (size_t)48*32*48*4);
static constexpr size_t OFF_NFPP= A256v(OFF_XN + (size_t)48*128*48*4);
static constexpr size_t OFF_NAC = A256v(OFF_NFPP + (size_t)48*48*4);

extern "C" void kernel_launch(void* const* d_in, const int* in_sizes, int n_in,
                              void* d_out, int out_size, void* d_ws, size_t ws_size,
                              hipStream_t stream) {
  const float* bi    = (const float*)d_in[0];
  const float* bij   = (const float*)d_in[1];
  const float* msgi  = (const float*)d_in[2];
  const float* msgj  = (const float*)d_in[3];
  const float* v_in  = (const float*)d_in[4];
  const float* nmem0 = (const float*)d_in[5];
  const float* emem0 = (const float*)d_in[6];
  const float* neadj = (const float*)d_in[7];
  const float* eeadj = (const float*)d_in[8];
  const int*   dec   = (const int*)d_in[13];
  const float* fm_w0 = (const float*)d_in[14]; const float* fm_b0 = (const float*)d_in[15];
  const float* fm_w1 = (const float*)d_in[16]; const float* fm_b1 = (const float*)d_in[17];
  const float* efm_w0= (const float*)d_in[18]; const float* efm_b0= (const float*)d_in[19];
  const float* efm_w1= (const float*)d_in[20]; const float* efm_b1= (const float*)d_in[21];
  const float* nl_w  = (const float*)d_in[22]; const float* nl_b  = (const float*)d_in[23];
  const float* el_w  = (const float*)d_in[24]; const float* el_b  = (const float*)d_in[25];
  const float* pp_w0 = (const float*)d_in[26]; const float* pp_b0 = (const float*)d_in[27];
  const float* pp_w1 = (const float*)d_in[28]; const float* pp_b1 = (const float*)d_in[29];
  const float* epp_w0= (const float*)d_in[30]; const float* epp_b0= (const float*)d_in[31];
  const float* epp_w1= (const float*)d_in[32]; const float* epp_b1= (const float*)d_in[33];

  char* ws = (char*)d_ws;
  unsigned short* eeadjb = (unsigned short*)(ws + OFF_EEADJ);
  unsigned short* x6t    = (unsigned short*)(ws + OFF_X6T);
  unsigned short* x32t   = (unsigned short*)(ws + OFF_X32T);
  unsigned short* x128t  = (unsigned short*)(ws + OFF_X128T);
  unsigned short* z1t    = x32t;
  unsigned short* z2t    = x6t;
  unsigned short* gatesT = x128t;
  unsigned short* yp6    = (unsigned short*)(ws + OFF_YP6);
  unsigned short* yp32   = (unsigned short*)(ws + OFF_YP32);
  unsigned short* yp128  = (unsigned short*)(ws + OFF_YP128);
  unsigned short* yp16   = (unsigned short*)(ws + OFF_YP16);
  unsigned short* xpp    = (unsigned short*)(ws + OFF_XPP);
  float*          skp    = (float*)(ws + OFF_SKP);
  unsigned short* wc0 = (unsigned short*)(ws + OFF_WC0);
  unsigned short* wc1 = (unsigned short*)(ws + OFF_WC1);
  unsigned short* wcl = (unsigned short*)(ws + OFF_WCL);
  unsigned short* wp0 = (unsigned short*)(ws + OFF_WP0);
  unsigned short* wp1 = (unsigned short*)(ws + OFF_WP1);
  float* cmi  = (float*)(ws + OFF_CMI);
  float* cmj  = (float*)(ws + OFF_CMJ);
  float* nmi  = (float*)(ws + OFF_NMI);
  float* nmj  = (float*)(ws + OFF_NMJ);
  float* effpp= (float*)(ws + OFF_EFPP);
  float* lse_e= (float*)(ws + OFF_LSEE);
  float* lse_n= (float*)(ws + OFF_LSEN);
  float* nvb  = (float*)(ws + OFF_NV);
  float* nf   = (float*)(ws + OFF_NF);
  float* nt1  = (float*)(ws + OFF_NT1);
  float* nt2  = (float*)(ws + OFF_NT2);
  float* nfeat  = (float*)(ws + OFF_NFEAT);
  float* nfeat2 = (float*)(ws + OFF_NFEAT2);
  float* xn   = (float*)(ws + OFF_XN);
  float* nfpp = (float*)(ws + OFF_NFPP);
  float* ncmi = (float*)(ws + OFF_NAC);
  float* ncmj = ncmi + 2304;
  float* nnmi = ncmi + 2*2304;
  float* nnmj = ncmi + 3*2304;

  float* out = (float*)d_out;
  float* o_bi   = out;
  float* o_bij  = out + 2304;
  float* o_mi   = out + 2304 + 5197824;
  float* o_mj   = o_mi + 108288;
  float* o_v    = o_mj + 108288;
  float* o_cd   = o_v + 48;
  float* o_nmem = o_cd + 1;
  float* o_emem = o_nmem + 147456;
  float* o_f1   = o_emem + 6930432;
  float* o_f2   = o_f1 + 2304;

  // 1. zero conv pad rows (yp128 pads re-zeroed later, after split-K reuse of its region)
  gm_zero_pads<<<EE, 128, 0, stream>>>(yp6, yp32, yp16);
  // 2. preps
  gm_prep_eeadj<<<(EP*EP+255)/256, 256, 0, stream>>>(eeadj, eeadjb);
  gm_prep_wall<<<(58880+255)/256, 256, 0, stream>>>(efm_w0, efm_w1, el_w, epp_w0, epp_w1,
                                                    wc0, wc1, wcl, wp0, wp1);
  // 3. messages
  gm_cmsg<<<EE, 128, 0, stream>>>(bi, bij, cmi, cmj);
  gm_node_accum<<<48, 256, 0, stream>>>(bij, cmi, cmj, msgi, msgj, dec, ncmi, ncmj, nnmi, nnmj, o_f1, o_f2);
  gm_build_x6<<<(288*EP+255)/256, 256, 0, stream>>>(msgi, msgj, cmi, cmj, bi, x6t);
  // 4. node feature CNN (wide-parallel map + conv)
  gm_build_nf<<<(48*8*48+255)/256, 256, 0, stream>>>(bi, v_in, nnmi, nnmj, ncmi, ncmj, o_f1, o_f2, nf);
  gm_nmap<<<(48*8*48+255)/256, 256, 0, stream>>>(neadj, nf, nt1, 8);
  gm_nconv<<<(48*32*48+255)/256, 256, 0, stream>>>(nt1, fm_w0, fm_b0, nt2, 8, 32, 1);
  gm_nmap<<<(48*32*48+255)/256, 256, 0, stream>>>(neadj, nt2, nt1, 32);
  gm_nconv<<<(48*32*48+255)/256, 256, 0, stream>>>(nt1, fm_w1, fm_b1, nfeat, 32, 32, 1);
  // 5. edge feature CNN
  gm_map_sk<<<216, 256, 0, stream>>>(eeadjb, x6t, skp, 18, 3, 4, 18);
  gm_sk_fin<<<(EE*288+255)/256, 256, 0, stream>>>(skp, yp6, nullptr, nullptr, 4, 384, 288, 6, 8, 0, 0);
  gm_conv_gemm<32><<<864, 256, 0, stream>>>(wc0, yp6,  x32t, efm_b0, 8, 8, 32, 32, 32, 1);
  gm_map_gemm<<<216, 256, 0, stream>>>(eeadjb, x32t, yp32, nullptr, nullptr, 18, 1536, 32, 32, 0, 0);
  gm_conv_gemm<32><<<864, 256, 0, stream>>>(wc1, yp32, x128t, efm_b1, 32, 32, 96, 32, 128, 1);
  // 6. fill LSTM input channels 32..127
  gm_fill_x128_hi<<<(96*EP+255)/256, 256, 0, stream>>>(emem0, nfeat, x128t);
  // 7. node LSTM (wide-parallel map, then fused gate-conv+pointwise)
  gm_xnode_copy<<<(48*64*48+255)/256, 256, 0, stream>>>(nfeat, nmem0, xn);
  gm_eton_x128<<<1536, 256, 0, stream>>>(x128t, xn);
  gm_nmap<<<(48*128*48+255)/256, 256, 0, stream>>>(neadj, xn, nt1, 128);
  gm_nconv_lstm<<<(48*32*48+255)/256, 256, 0, stream>>>(nt1, nl_w, nl_b, nmem0, o_nmem, nfeat2);
  // 8. edge LSTM (re-zero yp128 pads first: split-K partials clobbered them)
  gm_zero_pad128<<<EE, 128, 0, stream>>>(yp128);
  gm_map_gemm<<<864, 256, 0, stream>>>(eeadjb, x128t, yp128, nullptr, nullptr, 18, 6144, 128, 128, 0, 0);
  gm_conv_gemm<128><<<864, 256, 0, stream>>>(wcl, yp128, gatesT, el_b, 128, 128, 384, 128, 128, 0);
  gm_elstm_pw<<<564*6, 256, 0, stream>>>(gatesT, emem0, o_emem);
  // 9. epp (conv-first commute; bias after map; split-K for both maps)
  gm_build_xpp<<<EE, 128, 0, stream>>>(o_emem, nfeat2, xpp);
  gm_conv_gemm<16><<<864, 256, 0, stream>>>(wp0, xpp,  z1t, nullptr, 96, 96, 288, 16, 16, 0);
  gm_map_sk<<<432, 256, 0, stream>>>(eeadjb, z1t, skp, 18, 6, 4, 18);
  gm_sk_fin<<<(EE*768+255)/256, 256, 0, stream>>>(skp, yp16, nullptr, epp_b0, 4, 768, 768, 16, 16, 1, 0);
  gm_conv_gemm<16><<<864, 256, 0, stream>>>(wp1, yp16, z2t, nullptr, 16, 16, 64, 2, 2, 0);
  gm_map_sk<<<144, 256, 0, stream>>>(eeadjb, z2t, skp, 18, 1, 8, 9);
  gm_sk_fin<<<(EE*96+255)/256, 256, 0, stream>>>(skp, nullptr, effpp, epp_b1, 8, 128, 96, 2, 2, 0, 1);
  // 10. pp (node, wide-parallel map + conv)
  gm_x2_copy<<<(48*32*48+255)/256, 256, 0, stream>>>(nfeat2, xn);
  gm_eton_h<<<1536, 256, 0, stream>>>(o_emem, xn);
  gm_nmap<<<(48*96*48+255)/256, 256, 0, stream>>>(neadj, xn, nt1, 96);
  gm_nconv<<<(48*16*48+255)/256, 256, 0, stream>>>(nt1, pp_w0, pp_b0, nt2, 96, 16, 1);
  gm_nmap<<<(48*16*48+255)/256, 256, 0, stream>>>(neadj, nt2, nt1, 16);
  gm_nconv<<<(48*1*48+255)/256, 256, 0, stream>>>(nt1, pp_w1, pp_b1, nfpp, 16, 1, 0);
  // 11. outputs
  gm_nv<<<1, 64, 0, stream>>>(nfpp, v_in, nvb, o_v);
  gm_bijout<<<EE, 256, 0, stream>>>(bij, effpp, cmi, cmj, msgi, msgj, nmi, nmj, o_mi, o_mj, o_bij, lse_e);
  gm_biout<<<48, 64, 0, stream>>>(bi, nmi, nmj, nvb, o_bi, lse_n);
  gm_cdual<<<1, 256, 0, stream>>>(lse_e, lse_n, o_v, o_cd);
}

// Round 10
// 789.817 us; speedup vs baseline: 1.2761x; 1.0071x over previous
//
#include <hip/hip_runtime.h>
#include <cstdint>
#include <cstddef>

#define EE 2256
#define EP 2304

typedef __attribute__((ext_vector_type(8))) short bf16x8;
typedef __attribute__((ext_vector_type(4))) float f32x4;

__device__ __forceinline__ unsigned short f2b(float f){
  unsigned u = __builtin_bit_cast(unsigned, f);
  u += 0x7fffu + ((u>>16)&1u);
  return (unsigned short)(u>>16);
}
__device__ __forceinline__ float b2f(unsigned short h){
  unsigned u = ((unsigned)h)<<16; return __builtin_bit_cast(float, u);
}
__device__ __forceinline__ float sigm(float x){ return 1.f/(1.f+__expf(-x)); }
__device__ __forceinline__ float tanhfast(float x){ return 1.f - 2.f/(__expf(2.f*x)+1.f); }

// bijective XCD-chunked swizzle (m204)
__device__ __forceinline__ int xcd_swz(int bid, int nwg){
  int xcd = bid & 7, idx = bid >> 3;
  int q = nwg >> 3, r = nwg & 7;
  return (xcd < r ? xcd*(q+1) : r*(q+1) + (xcd-r)*q) + idx;
}

typedef __attribute__((address_space(3))) unsigned int lds_u32;
typedef __attribute__((address_space(1))) const unsigned int gbl_u32;
__device__ __forceinline__ void glds16(const void* g, void* l){
  __builtin_amdgcn_global_load_lds((gbl_u32*)g, (lds_u32*)l, 16, 0, 0);
}

// ---------------- utility kernels ----------------
__global__ __launch_bounds__(128) void gm_zero_pads(unsigned short* yp6, unsigned short* yp32,
                                                    unsigned short* yp16){
  int e = blockIdx.x; int tid = threadIdx.x;
  #pragma unroll
  for (int r=0; r<2; ++r){
    int row = r ? 49 : 0;
    if (tid < 8)  yp6 [((size_t)e*50+row)*8  + tid] = 0;
    if (tid < 32) yp32[((size_t)e*50+row)*32 + tid] = 0;
    if (tid < 16) yp16[((size_t)e*50+row)*16 + tid] = 0;
  }
}

__global__ __launch_bounds__(128) void gm_zero_pad128(unsigned short* yp128){
  int e = blockIdx.x; int tid = threadIdx.x;
  yp128[((size_t)e*50+0)*128 + tid] = 0;
  yp128[((size_t)e*50+49)*128 + tid] = 0;
}

__global__ void gm_prep_eeadj(const float* __restrict__ src, unsigned short* __restrict__ dst){
  int idx = blockIdx.x*256 + threadIdx.x;
  if (idx >= EP*EP) return;
  int r = idx / EP, k = idx - r*EP;
  float v = (r < EE && k < EE) ? src[(size_t)r*EE + k] : 0.f;
  dst[idx] = f2b(v);
}

__global__ void gm_prep_wall(const float* __restrict__ w0, const float* __restrict__ w1,
                             const float* __restrict__ w2, const float* __restrict__ w3,
                             const float* __restrict__ w4,
                             unsigned short* d0, unsigned short* d1, unsigned short* d2,
                             unsigned short* d3, unsigned short* d4){
  int idx = blockIdx.x*256 + threadIdx.x;
  const float* w; unsigned short* dp; int Co,Cin,KPT,Kpad,loc;
  if      (idx < 1024) { w=w0; dp=d0; Co=32;  Cin=6;   KPT=8;   Kpad=32;  loc=idx; }
  else if (idx < 4096) { w=w1; dp=d1; Co=32;  Cin=32;  KPT=32;  Kpad=96;  loc=idx-1024; }
  else if (idx < 53248){ w=w2; dp=d2; Co=128; Cin=128; KPT=128; Kpad=384; loc=idx-4096; }
  else if (idx < 57856){ w=w3; dp=d3; Co=16;  Cin=96;  KPT=96;  Kpad=288; loc=idx-53248; }
  else if (idx < 58880){ w=w4; dp=d4; Co=2;   Cin=16;  KPT=16;  Kpad=64;  loc=idx-57856; }
  else return;
  int co = loc / Kpad; int k = loc - co*Kpad;
  int t = k / KPT; int ci = k - t*KPT;
  float v = (co < Co && t < 3 && ci < Cin) ? w[((size_t)co*Cin + ci)*3 + t] : 0.f;
  dp[loc] = f2b(v);
}

// ---------------- message LSE kernels ----------------
__global__ __launch_bounds__(128) void gm_cmsg(const float* __restrict__ bi, const float* __restrict__ bij,
                                               float* __restrict__ cmi, float* __restrict__ cmj){
  int e = blockIdx.x; int tid = threadIdx.x;
  __shared__ float t[48*49]; __shared__ float bs[48], bd[48];
  const float* src = bij + (size_t)e*2304;
  for (int i=tid;i<2304;i+=128){ int r=i/48, c=i-r*48; t[r*49+c]=src[i]; }
  if (tid<48){ int s=e/47, m=e-s*47; int d=m+(m>=s); bs[tid]=bi[s*48+tid]; bd[tid]=bi[d*48+tid]; }
  __syncthreads();
  if (tid < 48){
    float mx=-1e30f;
    for (int n=0;n<48;n++) mx = fmaxf(mx, t[tid*49+n]+bd[n]);
    float sm=0.f;
    for (int n=0;n<48;n++) sm += __expf((t[tid*49+n]+bd[n]-mx)*20.f);
    cmi[e*48+tid] = mx + __logf(sm)*(1.f/20.f);
  } else if (tid>=64 && tid<112){
    int n = tid-64;
    float mx=-1e30f;
    for (int k=0;k<48;k++) mx = fmaxf(mx, t[k*49+n]+bs[k]);
    float sm=0.f;
    for (int k=0;k<48;k++) sm += __expf((t[k*49+n]+bs[k]-mx)*20.f);
    cmj[e*48+n] = mx + __logf(sm)*(1.f/20.f);
  }
}

__global__ __launch_bounds__(256) void gm_node_accum(const float* __restrict__ bij, const float* __restrict__ cmi,
                              const float* __restrict__ cmj, const float* __restrict__ msgi,
                              const float* __restrict__ msgj, const int* __restrict__ dec,
                              float* ncmi, float* ncmj, float* nnmi, float* nnmj,
                              float* o_f1, float* o_f2){
  int i = blockIdx.x; int tid = threadIdx.x;
  __shared__ float red[5][6][48];
  int mg = tid / 48;
  int w  = tid - mg*48;
  if (mg < 5){
    int dc = dec[i];
    float a1=0,a2=0,a3=0,a4=0,s1=0,s2=0;
    for (int m=mg; m<47; m+=5){
      int e1 = i*47+m;
      a1 += cmi[e1*48+w]; a3 += msgi[e1*48+w];
      s1 += bij[(size_t)e1*2304 + dc*48 + w];
      int j = m + (m>=i); int e2 = j*47 + i - (i>j);
      a2 += cmj[e2*48+w]; a4 += msgj[e2*48+w];
      s2 += bij[(size_t)e2*2304 + w*48 + dc];
    }
    red[mg][0][w]=a1; red[mg][1][w]=a2; red[mg][2][w]=a3;
    red[mg][3][w]=a4; red[mg][4][w]=s1; red[mg][5][w]=s2;
  }
  __syncthreads();
  if (tid < 48){
    float a1=0,a2=0,a3=0,a4=0,s1=0,s2=0;
    for (int g=0; g<5; g++){
      a1+=red[g][0][tid]; a2+=red[g][1][tid]; a3+=red[g][2][tid];
      a4+=red[g][3][tid]; s1+=red[g][4][tid]; s2+=red[g][5][tid];
    }
    ncmi[i*48+tid]=a1; ncmj[i*48+tid]=a2; nnmi[i*48+tid]=a3; nnmj[i*48+tid]=a4;
    o_f1[i*48+tid]=s1; o_f2[i*48+tid]=s2;
  }
}

// ---------------- staging builders ----------------
__global__ void gm_build_x6(const float* __restrict__ msgi, const float* __restrict__ msgj,
                            const float* __restrict__ cmi, const float* __restrict__ cmj,
                            const float* __restrict__ bi, unsigned short* __restrict__ x6){
  int idx = blockIdx.x*256 + threadIdx.x;
  if (idx >= 288*EP) return;
  int row = idx / EP, e = idx - row*EP;
  int w = row / 6, c = row - w*6;
  unsigned short val = 0;
  if (e < EE){
    int s = e/47, m = e-s*47, d = m + (m>=s);
    float x;
    switch(c){
      case 0: x = msgi[e*48+w]; break;
      case 1: x = msgj[e*48+w]; break;
      case 2: x = cmi[e*48+w]; break;
      case 3: x = cmj[e*48+w]; break;
      case 4: x = bi[s*48+w]; break;
      default: x = bi[d*48+w]; break;
    }
    val = f2b(x);
  }
  x6[idx] = val;
}

__global__ void gm_fill_x128_hi(const float* __restrict__ emem0, const float* __restrict__ nfeat,
                                unsigned short* __restrict__ x128){
  int idx = blockIdx.x*256 + threadIdx.x;
  if (idx >= 96*EP) return;
  int q = idx/EP; int c = 32 + q; int e = idx - q*EP;
  if (e >= EE){ for (int w=0;w<48;w++) x128[(size_t)(w*128+c)*EP + e] = 0; return; }
  int s=e/47, m=e-s*47, d=m+(m>=s);
  const float* srcrow;
  if (c < 64)      srcrow = nfeat + ((size_t)s*32 + (c-32))*48;
  else if (c < 96) srcrow = nfeat + ((size_t)d*32 + (c-64))*48;
  else             srcrow = emem0 + ((size_t)e*64 + (c-64))*48;
  #pragma unroll
  for (int w4=0; w4<12; w4++){
    float4 xv = *(const float4*)(srcrow + w4*4);
    x128[(size_t)((w4*4+0)*128+c)*EP + e] = f2b(xv.x);
    x128[(size_t)((w4*4+1)*128+c)*EP + e] = f2b(xv.y);
    x128[(size_t)((w4*4+2)*128+c)*EP + e] = f2b(xv.z);
    x128[(size_t)((w4*4+3)*128+c)*EP + e] = f2b(xv.w);
  }
}

// ---------------- MFMA map GEMM (BK=64 single-buffer, col-major XCD chunking) ----------------
// LDS layout [128][64] bf16; element (row, gcol_bytes) stored at byte row*128 + (gcol ^ ((row&7)<<4)).
__global__ __launch_bounds__(256) void gm_map_gemm(
    const unsigned short* __restrict__ A, const unsigned short* __restrict__ BT,
    unsigned short* __restrict__ ypad, float* __restrict__ outf,
    const float* __restrict__ bias, int nrow, int Nvalid, int Cch, int Cslab,
    int do_relu, int f32_out)
{
  __shared__ __align__(16) unsigned short lA[128*64];
  __shared__ __align__(16) unsigned short lB[128*64];
  const int tid = threadIdx.x;
  const int lane = tid & 63, wid = tid >> 6;
  const int swz = xcd_swz(blockIdx.x, gridDim.x);
  const int m0 = (swz % nrow) * 128;
  const int n0 = (swz / nrow) * 128;
  const int wm = wid >> 1, wn = wid & 1;
  f32x4 acc[4][4];
  #pragma unroll
  for (int i=0;i<4;i++){
    #pragma unroll
    for (int j=0;j<4;j++) acc[i][j] = f32x4{0.f,0.f,0.f,0.f};
  }
  const int srcc = (((lane&7) ^ (lane>>3))<<4);   // pre-swizzled global col for linear LDS dest

  for (int ks = 0; ks < EP/64; ++ks) {
    #pragma unroll
    for (int c = wid; c < 16; c += 4){
      int row = c*8 + (lane>>3);
      glds16((const char*)A  + (size_t)(m0+row)*(EP*2) + ks*128 + srcc, (char*)lA + c*1024);
      glds16((const char*)BT + (size_t)(n0+row)*(EP*2) + ks*128 + srcc, (char*)lB + c*1024);
    }
    __syncthreads();
    #pragma unroll
    for (int kk=0; kk<2; ++kk){
      bf16x8 af[4], bfr[4];
      #pragma unroll
      for (int mi=0;mi<4;mi++){
        int row = wm*64 + mi*16 + (lane&15);
        int sc = ((lane>>4)*16 + kk*64) ^ ((row&7)<<4);
        af[mi] = *(const bf16x8*)((const char*)lA + row*128 + sc);
      }
      #pragma unroll
      for (int ni=0;ni<4;ni++){
        int row = wn*64 + ni*16 + (lane&15);
        int sc = ((lane>>4)*16 + kk*64) ^ ((row&7)<<4);
        bfr[ni] = *(const bf16x8*)((const char*)lB + row*128 + sc);
      }
      #pragma unroll
      for (int mi=0;mi<4;mi++){
        #pragma unroll
        for (int ni=0;ni<4;ni++)
          acc[mi][ni] = __builtin_amdgcn_mfma_f32_16x16x32_bf16(af[mi], bfr[ni], acc[mi][ni], 0,0,0);
      }
    }
    __syncthreads();
  }
  #pragma unroll
  for (int mi=0;mi<4;mi++){
    int ebase = m0 + wm*64 + mi*16 + (lane>>4)*4;
    #pragma unroll
    for (int ni=0;ni<4;ni++){
      int c = n0 + wn*64 + ni*16 + (lane&15);
      if (c >= Nvalid) continue;
      int w = c / Cch, ci = c - w*Cch;
      float bv = bias ? bias[ci] : 0.f;
      #pragma unroll
      for (int r=0;r<4;r++){
        int e = ebase + r;
        if (e >= EE) continue;
        float x = acc[mi][ni][r] + bv;
        if (do_relu) x = fmaxf(x, 0.f);
        if (f32_out) outf[(size_t)e*Nvalid + c] = x;
        else ypad[((size_t)e*50 + 1 + w)*Cslab + ci] = f2b(x);
      }
    }
  }
}

// split-K variant (BK=64): kspan in units of 64; writes f32 partials pbuf[sp][e][c]
__global__ __launch_bounds__(256) void gm_map_sk(
    const unsigned short* __restrict__ A, const unsigned short* __restrict__ BT,
    float* __restrict__ pbuf, int nrow, int ncol, int S, int kspan)
{
  __shared__ __align__(16) unsigned short lA[128*64];
  __shared__ __align__(16) unsigned short lB[128*64];
  const int tid = threadIdx.x;
  const int lane = tid & 63, wid = tid >> 6;
  const int swz = xcd_swz(blockIdx.x, gridDim.x);
  const int ntile = nrow*ncol;
  const int sp = swz / ntile;
  const int tile = swz - sp*ntile;
  const int m0 = (tile % nrow) * 128;
  const int n0 = (tile / nrow) * 128;
  const int Npad = ncol*128;
  const int k0 = sp*kspan, k1 = k0 + kspan;
  const int wm = wid >> 1, wn = wid & 1;
  f32x4 acc[4][4];
  #pragma unroll
  for (int i=0;i<4;i++){
    #pragma unroll
    for (int j=0;j<4;j++) acc[i][j] = f32x4{0.f,0.f,0.f,0.f};
  }
  const int srcc = (((lane&7) ^ (lane>>3))<<4);

  for (int ks = k0; ks < k1; ++ks){
    #pragma unroll
    for (int c = wid; c < 16; c += 4){
      int row = c*8 + (lane>>3);
      glds16((const char*)A  + (size_t)(m0+row)*(EP*2) + ks*128 + srcc, (char*)lA + c*1024);
      glds16((const char*)BT + (size_t)(n0+row)*(EP*2) + ks*128 + srcc, (char*)lB + c*1024);
    }
    __syncthreads();
    #pragma unroll
    for (int kk=0; kk<2; ++kk){
      bf16x8 af[4], bfr[4];
      #pragma unroll
      for (int mi=0;mi<4;mi++){
        int row = wm*64 + mi*16 + (lane&15);
        int sc = ((lane>>4)*16 + kk*64) ^ ((row&7)<<4);
        af[mi] = *(const bf16x8*)((const char*)lA + row*128 + sc);
      }
      #pragma unroll
      for (int ni=0;ni<4;ni++){
        int row = wn*64 + ni*16 + (lane&15);
        int sc = ((lane>>4)*16 + kk*64) ^ ((row&7)<<4);
        bfr[ni] = *(const bf16x8*)((const char*)lB + row*128 + sc);
      }
      #pragma unroll
      for (int mi=0;mi<4;mi++){
        #pragma unroll
        for (int ni=0;ni<4;ni++)
          acc[mi][ni] = __builtin_amdgcn_mfma_f32_16x16x32_bf16(af[mi], bfr[ni], acc[mi][ni], 0,0,0);
      }
    }
    __syncthreads();
  }
  float* pb = pbuf + (size_t)sp*2304*Npad;
  #pragma unroll
  for (int mi=0;mi<4;mi++){
    int ebase = m0 + wm*64 + mi*16 + (lane>>4)*4;
    #pragma unroll
    for (int ni=0;ni<4;ni++){
      int c = n0 + wn*64 + ni*16 + (lane&15);
      #pragma unroll
      for (int r=0;r<4;r++)
        pb[(size_t)(ebase+r)*Npad + c] = acc[mi][ni][r];
    }
  }
}

__global__ void gm_sk_fin(const float* __restrict__ pbuf, unsigned short* __restrict__ ypad,
                          float* __restrict__ outf, const float* __restrict__ bias,
                          int S, int Npad, int Nvalid, int Cch, int Cslab, int do_relu, int f32_out){
  int idx = blockIdx.x*256 + threadIdx.x;
  if (idx >= EE*Nvalid) return;
  int e = idx / Nvalid, c = idx - e*Nvalid;
  float s = 0.f;
  for (int p=0;p<S;p++) s += pbuf[(size_t)p*2304*Npad + (size_t)e*Npad + c];
  int w = c / Cch, ci = c - w*Cch;
  if (bias) s += bias[ci];
  if (do_relu) s = fmaxf(s, 0.f);
  if (f32_out) outf[(size_t)e*Nvalid + c] = s;
  else ypad[((size_t)e*50 + 1 + w)*Cslab + ci] = f2b(s);
}

// ---------------- MFMA conv GEMM (operand-swapped, single-buffer, BK=32) ----------------
template<int BM>
__global__ __launch_bounds__(256) void gm_conv_gemm(
    const unsigned short* __restrict__ Wp, const unsigned short* __restrict__ ypad,
    unsigned short* __restrict__ outT, const float* __restrict__ bias,
    int Cch, int KPT, int Kpad, int Co, int Ct, int do_relu)
{
  constexpr int MI = (BM==128)?4:((BM==32)?2:1);
  constexpr int NI = (BM==128)?4:2;
  __shared__ __align__(16) unsigned short lA[BM*32];
  __shared__ __align__(16) unsigned short lB[128*32];
  const int tid = threadIdx.x, lane = tid&63, wid = tid>>6;
  const int swz = xcd_swz(blockIdx.x, 864);
  const int e0 = (swz / 48) * 128;
  const int w  = swz % 48;
  const int rowb = (BM==128)? (wid>>1)*64 : 0;
  const int colb = (BM==128)? (wid&1)*64 : wid*32;
  f32x4 acc[MI][NI];
  #pragma unroll
  for (int i=0;i<MI;i++){
    #pragma unroll
    for (int j=0;j<NI;j++) acc[i][j] = f32x4{0.f,0.f,0.f,0.f};
  }
  const int srow=(lane>>2), scol=(lane&3);
  const int ksteps = Kpad/32;
  for (int ks=0; ks<ksteps; ++ks){
    for (int c = wid; c < BM/16; c += 4){
      int row = c*16 + srow;
      int off = (scol*16) ^ (((row>>1)&3)<<4);
      glds16((const char*)Wp + (size_t)row*(Kpad*2) + ks*64 + off, (char*)lA + c*1024);
    }
    for (int c = wid; c < 8; c += 4){
      int row = c*16 + srow;
      int off = (scol*16) ^ (((row>>1)&3)<<4);
      int kg = ks*32 + (off>>1);
      int t = kg / KPT;
      int ci = kg - t*KPT;
      int e = e0 + row;
      const char* src;
      if (t < 3 && e < EE) src = (const char*)ypad + ((size_t)(e*50 + w + t)*Cch + ci)*2;
      else                 src = (const char*)ypad;
      glds16(src, (char*)lB + c*1024);
    }
    __syncthreads();
    bf16x8 af[MI], bfr[NI];
    #pragma unroll
    for (int mi=0;mi<MI;mi++){
      int row = rowb + mi*16 + (lane&15);
      int off = ((lane>>4)*16) ^ (((row>>1)&3)<<4);
      af[mi] = *(const bf16x8*)((const char*)lA + row*64 + off);
    }
    #pragma unroll
    for (int ni=0;ni<NI;ni++){
      int row = colb + ni*16 + (lane&15);
      int off = ((lane>>4)*16) ^ (((row>>1)&3)<<4);
      bfr[ni] = *(const bf16x8*)((const char*)lB + row*64 + off);
    }
    #pragma unroll
    for (int mi=0;mi<MI;mi++){
      #pragma unroll
      for (int ni=0;ni<NI;ni++)
        acc[mi][ni] = __builtin_amdgcn_mfma_f32_16x16x32_bf16(af[mi], bfr[ni], acc[mi][ni], 0,0,0);
    }
    __syncthreads();
  }
  #pragma unroll
  for (int mi=0;mi<MI;mi++){
    #pragma unroll
    for (int ni=0;ni<NI;ni++){
      int m = colb + ni*16 + (lane&15);
      int e = e0 + m;
      if (e >= EE) continue;
      #pragma unroll
      for (int r=0;r<4;r++){
        int co = rowb + mi*16 + (lane>>4)*4 + r;
        if (co >= Co) continue;
        float x = acc[mi][ni][r] + (bias ? bias[co] : 0.f);
        if (do_relu) x = fmaxf(x, 0.f);
        outT[((size_t)(w*Ct + co))*EP + e] = f2b(x);
      }
    }
  }
}

// ---------------- node-side kernels (wide-parallel) ----------------
__global__ void gm_build_nf(const float* __restrict__ bi, const float* __restrict__ v,
                            const float* __restrict__ nnmi, const float* __restrict__ nnmj,
                            const float* __restrict__ ncmi, const float* __restrict__ ncmj,
                            const float* __restrict__ f1, const float* __restrict__ f2,
                            float* __restrict__ nf){
  int idx = blockIdx.x*256+threadIdx.x;
  if (idx >= 48*8*48) return;
  int i = idx/(8*48); int rem = idx - i*(8*48); int c = rem/48; int w = rem-c*48;
  int iw = i*48+w;
  float x;
  switch(c){
    case 0: x=bi[iw]; break;
    case 1: x=bi[iw]+v[w]; break;
    case 2: x=nnmi[iw]; break;
    case 3: x=nnmj[iw]; break;
    case 4: x=ncmi[iw]; break;
    case 5: x=ncmj[iw]; break;
    case 6: x=f1[iw]; break;
    default: x=f2[iw]; break;
  }
  nf[idx]=x;
}

__global__ void gm_nmap(const float* __restrict__ adj, const float* __restrict__ X,
                        float* __restrict__ Y, int C){
  int idx = blockIdx.x*256 + threadIdx.x;
  int tot = 48*C*48;
  if (idx >= tot) return;
  int i = idx/(C*48); int rem = idx - i*(C*48);
  float s=0.f;
  for (int j=0;j<48;j++) s += adj[i*48+j]*X[(size_t)j*C*48 + rem];
  Y[idx]=s;
}

__global__ void gm_nconv(const float* __restrict__ X, const float* __restrict__ wgt,
                         const float* __restrict__ bias, float* __restrict__ Y,
                         int Cin, int Co, int relu){
  int idx = blockIdx.x*256 + threadIdx.x;
  int tot = 48*Co*48;
  if (idx >= tot) return;
  int i = idx/(Co*48); int rem = idx - i*(Co*48); int co = rem/48; int w = rem-co*48;
  float s = bias[co];
  const float* xb = X + (size_t)i*Cin*48;
  const float* wb = wgt + (size_t)co*Cin*3;
  for (int ci=0; ci<Cin; ++ci){
    float w0 = wb[ci*3], w1 = wb[ci*3+1], w2 = wb[ci*3+2];
    const float* xr = xb + ci*48;
    if (w > 0) s += xr[w-1]*w0;
    s += xr[w]*w1;
    if (w < 47) s += xr[w+1]*w2;
  }
  if (relu) s = fmaxf(s, 0.f);
  Y[idx] = s;
}

// fused 128->128 gate conv + LSTM pointwise (node side)
__global__ __launch_bounds__(256) void gm_nconv_lstm(const float* __restrict__ X,
    const float* __restrict__ wgt, const float* __restrict__ bias,
    const float* __restrict__ nmem0, float* __restrict__ o_nmem, float* __restrict__ nfeat2){
  int idx = blockIdx.x*256 + threadIdx.x;
  if (idx >= 48*32*48) return;
  int i = idx/(32*48); int rem = idx - i*(32*48); int ch = rem/48; int w = rem-ch*48;
  const float* xb = X + (size_t)i*128*48;
  float s0=bias[ch], s1=bias[32+ch], s2=bias[64+ch], s3=bias[96+ch];
  for (int ci=0; ci<128; ++ci){
    const float* xr = xb + ci*48;
    float xm = (w>0)? xr[w-1] : 0.f;
    float xc = xr[w];
    float xp = (w<47)? xr[w+1] : 0.f;
    const float* wb0 = wgt + ((size_t)ch*128+ci)*3;
    const float* wb1 = wgt + ((size_t)(32+ch)*128+ci)*3;
    const float* wb2 = wgt + ((size_t)(64+ch)*128+ci)*3;
    const float* wb3 = wgt + ((size_t)(96+ch)*128+ci)*3;
    s0 += xm*wb0[0]+xc*wb0[1]+xp*wb0[2];
    s1 += xm*wb1[0]+xc*wb1[1]+xp*wb1[2];
    s2 += xm*wb2[0]+xc*wb2[1]+xp*wb2[2];
    s3 += xm*wb3[0]+xc*wb3[1]+xp*wb3[2];
  }
  float c = nmem0[((size_t)i*64+ch)*48+w];
  float c2 = sigm(s1)*c + sigm(s0)*tanhfast(s2);
  float h2 = sigm(s3)*tanhfast(c2);
  o_nmem[((size_t)i*64+ch)*48+w] = c2;
  o_nmem[((size_t)i*64+32+ch)*48+w] = h2;
  nfeat2[((size_t)i*32+ch)*48+w] = h2;
}

// row-wise eton gathers from x128t efeat rows -> xn channels 32..95
__global__ __launch_bounds__(256) void gm_eton_x128(const unsigned short* __restrict__ x128,
                                                    float* __restrict__ xn){
  int row = blockIdx.x;          // w*32+cc
  int w = row >> 5, cc = row & 31;
  __shared__ float L[2256];
  const unsigned short* src = x128 + (size_t)(w*128 + cc)*EP;
  for (int t=threadIdx.x; t<2256; t+=256) L[t] = b2f(src[t]);
  __syncthreads();
  int tid = threadIdx.x;
  if (tid < 48){
    int i = tid; float s=0.f;
    for (int m=0;m<47;m++) s += L[i*47+m];
    xn[((size_t)i*128 + 32 + cc)*48 + w] = s;
  } else if (tid >= 64 && tid < 112){
    int i = tid-64; float s=0.f;
    for (int m=0;m<47;m++){
      int j = m + (m>=i);
      s += L[j*47 + i - (i>j)];
    }
    xn[((size_t)i*128 + 64 + cc)*48 + w] = s;
  }
}

__global__ void gm_xnode_copy(const float* __restrict__ nfeat, const float* __restrict__ nmem0,
                              float* __restrict__ xn){
  int idx = blockIdx.x*256+threadIdx.x;
  if (idx >= 48*64*48) return;
  int i = idx/(64*48); int rem = idx - i*(64*48); int c = rem/48; int w = rem-c*48;
  if (c < 32) xn[((size_t)i*128 + c)*48 + w] = nfeat[((size_t)i*32+c)*48+w];
  else        xn[((size_t)i*128 + 96 + (c-32))*48 + w] = nmem0[((size_t)i*64 + 32 + (c-32))*48 + w];
}

// edge LSTM pointwise; also writes xpp channels 0..31 (= h) directly
__global__ __launch_bounds__(256) void gm_elstm_pw(const unsigned short* __restrict__ gatesT,
                                                   const float* __restrict__ emem0,
                                                   float* __restrict__ o_emem,
                                                   unsigned short* __restrict__ xpp){
  int bid = blockIdx.x;
  int e4 = bid / 6, chunk = bid - e4*6;
  int cw = chunk*256 + threadIdx.x;
  int ch = cw / 48, w = cw - ch*48;
  int ebase = e4*4;
  const unsigned short* g0 = gatesT + (size_t)(w*128 + ch)*EP + ebase;
  ushort4 vi = *(const ushort4*)(g0);
  ushort4 vf = *(const ushort4*)(g0 + (size_t)32*EP);
  ushort4 vg = *(const ushort4*)(g0 + (size_t)64*EP);
  ushort4 vo = *(const ushort4*)(g0 + (size_t)96*EP);
  const unsigned short* pi = (const unsigned short*)&vi;
  const unsigned short* pf = (const unsigned short*)&vf;
  const unsigned short* pg = (const unsigned short*)&vg;
  const unsigned short* po = (const unsigned short*)&vo;
  #pragma unroll
  for (int r=0;r<4;r++){
    int e = ebase + r;
    float gi = b2f(pi[r]), gf = b2f(pf[r]), gg = b2f(pg[r]), go = b2f(po[r]);
    float c  = emem0[((size_t)e*64 + ch)*48 + w];
    float c2 = sigm(gf)*c + sigm(gi)*tanhfast(gg);
    float h2 = sigm(go)*tanhfast(c2);
    o_emem[((size_t)e*64 + ch)*48 + w] = c2;
    o_emem[((size_t)e*64 + 32+ch)*48 + w] = h2;
    xpp[((size_t)e*50 + 1 + w)*96 + ch] = f2b(h2);
  }
}

__global__ __launch_bounds__(256) void gm_eton_h(const float* __restrict__ o_emem,
                                                 float* __restrict__ x2){
  int row = blockIdx.x; int w = row >> 5, cc = row & 31;
  __shared__ float L[2256];
  for (int t=threadIdx.x; t<2256; t+=256)
    L[t] = o_emem[((size_t)t*64 + 32 + cc)*48 + w];
  __syncthreads();
  int tid = threadIdx.x;
  if (tid < 48){
    int i=tid; float s=0.f;
    for (int m=0;m<47;m++) s += L[i*47+m];
    x2[((size_t)i*96 + 32 + cc)*48 + w] = s;
  } else if (tid>=64 && tid<112){
    int i=tid-64; float s=0.f;
    for (int m=0;m<47;m++){ int j=m+(m>=i); s += L[j*47 + i - (i>j)]; }
    x2[((size_t)i*96 + 64 + cc)*48 + w] = s;
  }
}

__global__ void gm_x2_copy(const float* __restrict__ nfeat2, float* __restrict__ x2){
  int idx = blockIdx.x*256+threadIdx.x;
  if (idx >= 48*32*48) return;
  int i = idx/(32*48); int rem = idx - i*(32*48); int c = rem/48; int w = rem-c*48;
  x2[((size_t)i*96 + c)*48 + w] = nfeat2[idx];
}

// fill xpp channels 32..95 from nfeat2 + zero pad rows (channels 0..31 written by elstm_pw)
__global__ __launch_bounds__(128) void gm_build_xpp2(const float* __restrict__ nfeat2,
                                                     unsigned short* __restrict__ xpp){
  int e = blockIdx.x; int tid = threadIdx.x;
  __shared__ float sn[3072];
  int s = e/47; int m = e - s*47; int d = m + (m>=s);
  const float* ps = nfeat2 + (size_t)s*32*48;
  const float* pd = nfeat2 + (size_t)d*32*48;
  for (int i=tid;i<1536;i+=128){ sn[i]=ps[i]; sn[1536+i]=pd[i]; }
  if (tid < 96){
    xpp[((size_t)e*50 + 0)*96 + tid] = 0;
    xpp[((size_t)e*50 + 49)*96 + tid] = 0;
  }
  __syncthreads();
  for (int w=0; w<48; w++){
    if (tid < 64){
      xpp[((size_t)e*50 + 1 + w)*96 + 32 + tid] = f2b(sn[tid*48 + w]);
    }
  }
}

__global__ void gm_nv(const float* __restrict__ nfpp, const float* __restrict__ v,
                      float* __restrict__ nv, float* __restrict__ o_v){
  int w = threadIdx.x;
  if (w<48){
    float s=0.f; for (int i=0;i<48;i++) s += nfpp[i*48+w];
    s *= (1.f/48.f);
    nv[w]=s; o_v[w]=v[w]+s;
  }
}

// fused: nmsg + bij output + edge LSE
__global__ __launch_bounds__(256) void gm_bijout(const float* __restrict__ bij,
                                                 const float* __restrict__ effpp,
                                                 const float* __restrict__ cmi, const float* __restrict__ cmj,
                                                 const float* __restrict__ msgi, const float* __restrict__ msgj,
                                                 float* __restrict__ nmi, float* __restrict__ nmj,
                                                 float* __restrict__ o_mi, float* __restrict__ o_mj,
                                                 float* __restrict__ o_bij, float* __restrict__ lse_e){
  int e = blockIdx.x; int tid = threadIdx.x;
  __shared__ float ri[48], rj[48], red[8];
  if (tid < 48){
    int idx = e*48+tid;
    float a = effpp[(size_t)e*96 + tid*2] + 0.5f*cmi[idx] - msgi[idx];
    ri[tid] = a; nmi[idx] = a; o_mi[idx] = msgi[idx] + a;
  } else if (tid >= 64 && tid < 112){
    int t2 = tid-64; int idx = e*48+t2;
    float b = effpp[(size_t)e*96 + t2*2 + 1] + 0.5f*cmj[idx] - msgj[idx];
    rj[t2] = b; nmj[idx] = b; o_mj[idx] = msgj[idx] + b;
  }
  __syncthreads();
  float v[9]; float mx = -1e30f;
  const float* src = bij + (size_t)e*2304;
  float* dst = o_bij + (size_t)e*2304;
  #pragma unroll
  for (int q=0;q<9;q++){
    int idx = q*256 + tid;
    int r = idx/48, c = idx-r*48;
    float x = src[idx] - ri[r] - rj[c];
    dst[idx] = x; v[q] = x; mx = fmaxf(mx, x);
  }
  for (int o=1;o<64;o<<=1) mx = fmaxf(mx, __shfl_xor(mx, o, 64));
  int lane = tid&63, w4 = tid>>6;
  if (lane==0) red[w4] = mx;
  __syncthreads();
  mx = fmaxf(fmaxf(red[0],red[1]),fmaxf(red[2],red[3]));
  float s = 0.f;
  #pragma unroll
  for (int q=0;q<9;q++) s += __expf((v[q]-mx)*20.f);
  for (int o=1;o<64;o<<=1) s += __shfl_xor(s, o, 64);
  if (lane==0) red[4+w4] = s;
  __syncthreads();
  if (tid==0){
    float t = red[4]+red[5]+red[6]+red[7];
    lse_e[e] = mx + __logf(t)*(1.f/20.f);
  }
}

__global__ void gm_biout(const float* __restrict__ bi, const float* __restrict__ nmi,
                         const float* __restrict__ nmj, const float* __restrict__ nv,
                         float* __restrict__ o_bi, float* __restrict__ lse_n){
  int i = blockIdx.x; int w = threadIdx.x;
  float val = -1e30f;
  if (w < 48){
    float s = 0.f;
    for (int m=0;m<47;m++){
      int e1 = i*47+m;
      s += nmi[e1*48+w];
      int j = m + (m>=i);
      int e2 = j*47 + i - (i>j);
      s += nmj[e2*48+w];
    }
    val = bi[i*48+w] + s - nv[w];
    o_bi[i*48+w] = val;
  }
  float mx = val;
  for (int o=1;o<64;o<<=1) mx = fmaxf(mx, __shfl_xor(mx, o, 64));
  float ex = (w<48)? __expf((val-mx)*20.f) : 0.f;
  for (int o=1;o<64;o<<=1) ex += __shfl_xor(ex, o, 64);
  if (w==0) lse_n[i] = mx + __logf(ex)*(1.f/20.f);
}

__global__ void gm_cdual(const float* __restrict__ lse_e, const float* __restrict__ lse_n,
                         const float* __restrict__ vout, float* __restrict__ out){
  int tid = threadIdx.x;
  float s = 0.f;
  for (int i=tid;i<EE;i+=256) s += lse_e[i];
  if (tid<48) s += lse_n[tid] + vout[tid];
  __shared__ float red[4];
  for (int o=1;o<64;o<<=1) s += __shfl_xor(s,o,64);
  if ((tid&63)==0) red[tid>>6]=s;
  __syncthreads();
  if (tid==0) out[0] = red[0]+red[1]+red[2]+red[3];
}

// ---------------- workspace layout ----------------
static constexpr size_t A256v(size_t x){ return (x+255)&~(size_t)255; }
static constexpr size_t OFF_EEADJ = 0;
static constexpr size_t OFF_X6T   = A256v(OFF_EEADJ + (size_t)EP*EP*2);
static constexpr size_t OFF_X32T  = A256v(OFF_X6T  + (size_t)384*EP*2);
static constexpr size_t OFF_X128T = A256v(OFF_X32T + (size_t)1536*EP*2);
static constexpr size_t OFF_YP6   = A256v(OFF_X128T + (size_t)6144*EP*2);
static constexpr size_t OFF_YP32  = A256v(OFF_YP6  + (size_t)EE*50*8*2);
static constexpr size_t OFF_YP128 = A256v(OFF_YP32 + (size_t)EE*50*32*2);
static constexpr size_t OFF_YP16  = A256v(OFF_YP128 + (size_t)EE*50*128*2);
static constexpr size_t OFF_ZEND  = A256v(OFF_YP16 + (size_t)EE*50*16*2 + 256);
static constexpr size_t OFF_XPP   = OFF_YP128;
static constexpr size_t OFF_SKP   = OFF_YP128;
static constexpr size_t OFF_WC0 = OFF_ZEND;
static constexpr size_t OFF_WC1 = A256v(OFF_WC0 + 32*32*2);
static constexpr size_t OFF_WCL = A256v(OFF_WC1 + 32*96*2);
static constexpr size_t OFF_WP0 = A256v(OFF_WCL + 128*384*2);
static constexpr size_t OFF_WP1 = A256v(OFF_WP0 + 16*288*2);
static constexpr size_t OFF_CMI = A256v(OFF_WP1 + 16*64*2);
static constexpr size_t OFF_CMJ = A256v(OFF_CMI + (size_t)EE*48*4);
static constexpr size_t OFF_NMI = A256v(OFF_CMJ + (size_t)EE*48*4);
static constexpr size_t OFF_NMJ = A256v(OFF_NMI + (size_t)EE*48*4);
static constexpr size_t OFF_EFPP= A256v(OFF_NMJ + (size_t)EE*48*4);
static constexpr size_t OFF_LSEE= A256v(OFF_EFPP + (size_t)EE*96*4);
static constexpr size_t OFF_LSEN= A256v(OFF_LSEE + EE*4);
static constexpr size_t OFF_NV  = A256v(OFF_LSEN + 48*4);
static constexpr size_t OFF_NF  = A256v(OFF_NV + 48*4);
static constexpr size_t OFF_NT1 = A256v(OFF_NF + (size_t)48*8*48*4);
static constexpr size_t OFF_NT2 = A256v(OFF_NT1 + (size_t)48*128*48*4);
static constexpr size_t OFF_NFEAT = A256v(OFF_NT2 + (size_t)48*32*48*4);
static constexpr size_t OFF_NFEAT2= A256v(OFF_NFEAT + (size_t)48*32*48*4);
static constexpr size_t OFF_XN  = A256v(OFF_NFEAT2 + (size_t)48*32*48*4);
static constexpr size_t OFF_NFPP= A256v(OFF_XN + (size_t)48*128*48*4);
static constexpr size_t OFF_NAC = A256v(OFF_NFPP + (size_t)48*48*4);

extern "C" void kernel_launch(void* const* d_in, const int* in_sizes, int n_in,
                              void* d_out, int out_size, void* d_ws, size_t ws_size,
                              hipStream_t stream) {
  const float* bi    = (const float*)d_in[0];
  const float* bij   = (const float*)d_in[1];
  const float* msgi  = (const float*)d_in[2];
  const float* msgj  = (const float*)d_in[3];
  const float* v_in  = (const float*)d_in[4];
  const float* nmem0 = (const float*)d_in[5];
  const float* emem0 = (const float*)d_in[6];
  const float* neadj = (const float*)d_in[7];
  const float* eeadj = (const float*)d_in[8];
  const int*   dec   = (const int*)d_in[13];
  const float* fm_w0 = (const float*)d_in[14]; const float* fm_b0 = (const float*)d_in[15];
  const float* fm_w1 = (const float*)d_in[16]; const float* fm_b1 = (const float*)d_in[17];
  const float* efm_w0= (const float*)d_in[18]; const float* efm_b0= (const float*)d_in[19];
  const float* efm_w1= (const float*)d_in[20]; const float* efm_b1= (const float*)d_in[21];
  const float* nl_w  = (const float*)d_in[22]; const float* nl_b  = (const float*)d_in[23];
  const float* el_w  = (const float*)d_in[24]; const float* el_b  = (const float*)d_in[25];
  const float* pp_w0 = (const float*)d_in[26]; const float* pp_b0 = (const float*)d_in[27];
  const float* pp_w1 = (const float*)d_in[28]; const float* pp_b1 = (const float*)d_in[29];
  const float* epp_w0= (const float*)d_in[30]; const float* epp_b0= (const float*)d_in[31];
  const float* epp_w1= (const float*)d_in[32]; const float* epp_b1= (const float*)d_in[33];

  char* ws = (char*)d_ws;
  unsigned short* eeadjb = (unsigned short*)(ws + OFF_EEADJ);
  unsigned short* x6t    = (unsigned short*)(ws + OFF_X6T);
  unsigned short* x32t   = (unsigned short*)(ws + OFF_X32T);
  unsigned short* x128t  = (unsigned short*)(ws + OFF_X128T);
  unsigned short* z1t    = x32t;
  unsigned short* z2t    = x6t;
  unsigned short* gatesT = x128t;
  unsigned short* yp6    = (unsigned short*)(ws + OFF_YP6);
  unsigned short* yp32   = (unsigned short*)(ws + OFF_YP32);
  unsigned short* yp128  = (unsigned short*)(ws + OFF_YP128);
  unsigned short* yp16   = (unsigned short*)(ws + OFF_YP16);
  unsigned short* xpp    = (unsigned short*)(ws + OFF_XPP);
  float*          skp    = (float*)(ws + OFF_SKP);
  unsigned short* wc0 = (unsigned short*)(ws + OFF_WC0);
  unsigned short* wc1 = (unsigned short*)(ws + OFF_WC1);
  unsigned short* wcl = (unsigned short*)(ws + OFF_WCL);
  unsigned short* wp0 = (unsigned short*)(ws + OFF_WP0);
  unsigned short* wp1 = (unsigned short*)(ws + OFF_WP1);
  float* cmi  = (float*)(ws + OFF_CMI);
  float* cmj  = (float*)(ws + OFF_CMJ);
  float* nmi  = (float*)(ws + OFF_NMI);
  float* nmj  = (float*)(ws + OFF_NMJ);
  float* effpp= (float*)(ws + OFF_EFPP);
  float* lse_e= (float*)(ws + OFF_LSEE);
  float* lse_n= (float*)(ws + OFF_LSEN);
  float* nvb  = (float*)(ws + OFF_NV);
  float* nf   = (float*)(ws + OFF_NF);
  float* nt1  = (float*)(ws + OFF_NT1);
  float* nt2  = (float*)(ws + OFF_NT2);
  float* nfeat  = (float*)(ws + OFF_NFEAT);
  float* nfeat2 = (float*)(ws + OFF_NFEAT2);
  float* xn   = (float*)(ws + OFF_XN);
  float* nfpp = (float*)(ws + OFF_NFPP);
  float* ncmi = (float*)(ws + OFF_NAC);
  float* ncmj = ncmi + 2304;
  float* nnmi = ncmi + 2*2304;
  float* nnmj = ncmi + 3*2304;

  float* out = (float*)d_out;
  float* o_bi   = out;
  float* o_bij  = out + 2304;
  float* o_mi   = out + 2304 + 5197824;
  float* o_mj   = o_mi + 108288;
  float* o_v    = o_mj + 108288;
  float* o_cd   = o_v + 48;
  float* o_nmem = o_cd + 1;
  float* o_emem = o_nmem + 147456;
  float* o_f1   = o_emem + 6930432;
  float* o_f2   = o_f1 + 2304;

  // 1. zero conv pad rows (yp128 pads re-zeroed later, after split-K reuse of its region)
  gm_zero_pads<<<EE, 128, 0, stream>>>(yp6, yp32, yp16);
  // 2. preps
  gm_prep_eeadj<<<(EP*EP+255)/256, 256, 0, stream>>>(eeadj, eeadjb);
  gm_prep_wall<<<(58880+255)/256, 256, 0, stream>>>(efm_w0, efm_w1, el_w, epp_w0, epp_w1,
                                                    wc0, wc1, wcl, wp0, wp1);
  // 3. messages
  gm_cmsg<<<EE, 128, 0, stream>>>(bi, bij, cmi, cmj);
  gm_node_accum<<<48, 256, 0, stream>>>(bij, cmi, cmj, msgi, msgj, dec, ncmi, ncmj, nnmi, nnmj, o_f1, o_f2);
  gm_build_x6<<<(288*EP+255)/256, 256, 0, stream>>>(msgi, msgj, cmi, cmj, bi, x6t);
  // 4. node feature CNN (wide-parallel map + conv)
  gm_build_nf<<<(48*8*48+255)/256, 256, 0, stream>>>(bi, v_in, nnmi, nnmj, ncmi, ncmj, o_f1, o_f2, nf);
  gm_nmap<<<(48*8*48+255)/256, 256, 0, stream>>>(neadj, nf, nt1, 8);
  gm_nconv<<<(48*32*48+255)/256, 256, 0, stream>>>(nt1, fm_w0, fm_b0, nt2, 8, 32, 1);
  gm_nmap<<<(48*32*48+255)/256, 256, 0, stream>>>(neadj, nt2, nt1, 32);
  gm_nconv<<<(48*32*48+255)/256, 256, 0, stream>>>(nt1, fm_w1, fm_b1, nfeat, 32, 32, 1);
  // 5. edge feature CNN (kspan now in BK=64 units; EP/64 = 36 total steps)
  gm_map_sk<<<216, 256, 0, stream>>>(eeadjb, x6t, skp, 18, 3, 4, 9);
  gm_sk_fin<<<(EE*288+255)/256, 256, 0, stream>>>(skp, yp6, nullptr, nullptr, 4, 384, 288, 6, 8, 0, 0);
  gm_conv_gemm<32><<<864, 256, 0, stream>>>(wc0, yp6,  x32t, efm_b0, 8, 8, 32, 32, 32, 1);
  gm_map_gemm<<<216, 256, 0, stream>>>(eeadjb, x32t, yp32, nullptr, nullptr, 18, 1536, 32, 32, 0, 0);
  gm_conv_gemm<32><<<864, 256, 0, stream>>>(wc1, yp32, x128t, efm_b1, 32, 32, 96, 32, 128, 1);
  // 6. fill LSTM input channels 32..127
  gm_fill_x128_hi<<<(96*EP+255)/256, 256, 0, stream>>>(emem0, nfeat, x128t);
  // 7. node LSTM (wide-parallel map, then fused gate-conv+pointwise)
  gm_xnode_copy<<<(48*64*48+255)/256, 256, 0, stream>>>(nfeat, nmem0, xn);
  gm_eton_x128<<<1536, 256, 0, stream>>>(x128t, xn);
  gm_nmap<<<(48*128*48+255)/256, 256, 0, stream>>>(neadj, xn, nt1, 128);
  gm_nconv_lstm<<<(48*32*48+255)/256, 256, 0, stream>>>(nt1, nl_w, nl_b, nmem0, o_nmem, nfeat2);
  // 8. edge LSTM (re-zero yp128 pads first: split-K partials clobbered them)
  gm_zero_pad128<<<EE, 128, 0, stream>>>(yp128);
  gm_map_gemm<<<864, 256, 0, stream>>>(eeadjb, x128t, yp128, nullptr, nullptr, 18, 6144, 128, 128, 0, 0);
  gm_conv_gemm<128><<<864, 256, 0, stream>>>(wcl, yp128, gatesT, el_b, 128, 128, 384, 128, 128, 0);
  gm_elstm_pw<<<564*6, 256, 0, stream>>>(gatesT, emem0, o_emem, xpp);
  // 9. epp (conv-first commute; elstm_pw wrote xpp ch0..31; fill 32..95 + pads)
  gm_build_xpp2<<<EE, 128, 0, stream>>>(nfeat2, xpp);
  gm_conv_gemm<16><<<864, 256, 0, stream>>>(wp0, xpp,  z1t, nullptr, 96, 96, 288, 16, 16, 0);
  gm_map_sk<<<432, 256, 0, stream>>>(eeadjb, z1t, skp, 18, 6, 4, 9);
  gm_sk_fin<<<(EE*768+255)/256, 256, 0, stream>>>(skp, yp16, nullptr, epp_b0, 4, 768, 768, 16, 16, 1, 0);
  gm_conv_gemm<16><<<864, 256, 0, stream>>>(wp1, yp16, z2t, nullptr, 16, 16, 64, 2, 2, 0);
  gm_map_sk<<<216, 256, 0, stream>>>(eeadjb, z2t, skp, 18, 1, 12, 3);
  gm_sk_fin<<<(EE*96+255)/256, 256, 0, stream>>>(skp, nullptr, effpp, epp_b1, 12, 128, 96, 2, 2, 0, 1);
  // 10. pp (node, wide-parallel map + conv)
  gm_x2_copy<<<(48*32*48+255)/256, 256, 0, stream>>>(nfeat2, xn);
  gm_eton_h<<<1536, 256, 0, stream>>>(o_emem, xn);
  gm_nmap<<<(48*96*48+255)/256, 256, 0, stream>>>(neadj, xn, nt1, 96);
  gm_nconv<<<(48*16*48+255)/256, 256, 0, stream>>>(nt1, pp_w0, pp_b0, nt2, 96, 16, 1);
  gm_nmap<<<(48*16*48+255)/256, 256, 0, stream>>>(neadj, nt2, nt1, 16);
  gm_nconv<<<(48*1*48+255)/256, 256, 0, stream>>>(nt1, pp_w1, pp_b1, nfpp, 16, 1, 0);
  // 11. outputs
  gm_nv<<<1, 64, 0, stream>>>(nfpp, v_in, nvb, o_v);
  gm_bijout<<<EE, 256, 0, stream>>>(bij, effpp, cmi, cmj, msgi, msgj, nmi, nmj, o_mi, o_mj, o_bij, lse_e);
  gm_biout<<<48, 64, 0, stream>>>(bi, nmi, nmj, nvb, o_bi, lse_n);
  gm_cdual<<<1, 256, 0, stream>>>(lse_e, lse_n, o_v, o_cd);
}